// Round 4
// baseline (860.913 us; speedup 1.0000x reference)
//
#include <hip/hip_runtime.h>
#include <hip/hip_bf16.h>

using bf16 = __hip_bfloat16;

#define TOB(x) __float2bfloat16(x)

// problem constants (fixed by harness shapes)
#define NS   4
#define NPX  4096
#define NSZ  24
#define EMB  206
#define PS   64

// out element offsets (dtype-independent)
#define OFF0 0        // ref_novel_view (3,4096)
#define OFF1 12288    // blended_img    (3,4096)
#define OFF2 24576    // interp_view    (4,3,4096)
#define OFF3 73728    // weight         (4,4096,24)
#define OFF4 466944   // confs          (4,4096)

// ---------------------------------------------------------------------------
// Static device-global scratch (f32, ~17 MB). Not using d_ws (rounds 1-2) and
// globals alone (round 3) both NaN'd => failure is in INPUT interpretation,
// not scratch. Scratch stays here: fully rewritten every call before read.
// ---------------------------------------------------------------------------
__device__ float g_ce  [NS * 64 * NPX];   // flowRefNet output (relu)
__device__ float g_ctx [NS * 64 * NPX];   // ctxNet output (relu)
__device__ float g_ictx[NS * 64 * NPX];   // interp_ctx, [s*64+k][p]
__device__ float g_pf  [NS * 64 * NPX];   // psv_feat mean over D, [s*64+oc][p]
__device__ float g_iv  [NS * NPX * 3];    // interp_view, [s][p][c]
__device__ float g_clg [NS * NPX];        // confNet logit per (source,pixel)
__device__ float g_bl  [3 * NPX];         // blended image, [c][p]
__device__ int   g_isf32;                 // 1 = float inputs/outputs, 0 = bf16

__device__ __forceinline__ int clampi(int v, int lo, int hi) {
    return v < lo ? lo : (v > hi ? hi : v);
}

// dtype-dispatched load/store: element index i into tensor p
__device__ __forceinline__ float ldv(const void* p, int i, bool f32) {
    if (f32) return ((const float*)p)[i];
    unsigned u = ((const unsigned short*)p)[i];
    return __uint_as_float(u << 16);
}
__device__ __forceinline__ void stv(void* p, int i, float v, bool f32) {
    if (f32) ((float*)p)[i] = v;
    else     ((bf16*)p)[i] = TOB(v);
}

// ---------------------------------------------------------------------------
// Kernel 0: input dtype detection. f32 data read as bf16 shows random-exponent
// garbage (low mantissa halves land on the bf16 exponent field); bf16 data read
// as bf16 is ~N(0,1). Flag f32 iff any of the first 512 bf16-decoded values is
// huge/non-finite. (bf16-as-f32 looks sane, so this direction is the robust one.)
// ---------------------------------------------------------------------------
__global__ void k_detect(const void* sv) {
    if (threadIdx.x == 0 && blockIdx.x == 0) {
        const unsigned short* ph = (const unsigned short*)sv;
        float mh = 0.f;
        for (int i = 0; i < 512; ++i) {
            float b = __uint_as_float(((unsigned)ph[i]) << 16);
            float a = fabsf(b);
            if (!(a < 1e30f)) a = 1e30f;   // NaN/Inf counts as huge
            mh = fmaxf(mh, a);
        }
        g_isf32 = (mh > 1e6f) ? 1 : 0;
    }
}

// ---------------------------------------------------------------------------
// Kernel 1: ce = relu(conv3x3(cat[sf(6),sv(3),wv(9)], flow_w)) ; ctx = relu(conv3x3(sv, ctx_w))
// grid 16384 (s*npx), block 64 (lane = out channel)
// ---------------------------------------------------------------------------
__global__ __launch_bounds__(64) void k_convs(
    const void* __restrict__ sv, const void* __restrict__ sf, const void* __restrict__ wv,
    const void* __restrict__ flow_w, const void* __restrict__ flow_b,
    const void* __restrict__ ctx_w, const void* __restrict__ ctx_b)
{
    const bool F = (g_isf32 != 0);
    const int blk = blockIdx.x;
    const int b = blk >> 12, p = blk & 4095;
    const int py = p >> 6, px = p & 63;
    const int oc = threadIdx.x;

    float acc_ce = 0.f, acc_ctx = 0.f;
    #pragma unroll
    for (int ky = 0; ky < 3; ++ky) {
        const int iy = py + ky - 1;
        if ((unsigned)iy >= 64u) continue;
        #pragma unroll
        for (int kx = 0; kx < 3; ++kx) {
            const int ix = px + kx - 1;
            if ((unsigned)ix >= 64u) continue;
            const int q = iy * 64 + ix;
            const int t = ky * 3 + kx;
            #pragma unroll
            for (int ic = 0; ic < 6; ++ic)
                acc_ce += ldv(sf, (b * 6 + ic) * NPX + q, F) * ldv(flow_w, (oc * 18 + ic) * 9 + t, F);
            #pragma unroll
            for (int ic = 0; ic < 3; ++ic) {
                float v = ldv(sv, (b * 3 + ic) * NPX + q, F);
                acc_ce  += v * ldv(flow_w, (oc * 18 + 6 + ic) * 9 + t, F);
                acc_ctx += v * ldv(ctx_w, (oc * 3 + ic) * 9 + t, F);
            }
            #pragma unroll
            for (int ic = 0; ic < 9; ++ic)
                acc_ce += ldv(wv, (b * 9 + ic) * NPX + q, F) * ldv(flow_w, (oc * 18 + 9 + ic) * 9 + t, F);
        }
    }
    acc_ce  += ldv(flow_b, oc, F);
    acc_ctx += ldv(ctx_b, oc, F);
    g_ce [(b * 64 + oc) * NPX + p] = fmaxf(acc_ce, 0.f);
    g_ctx[(b * 64 + oc) * NPX + p] = fmaxf(acc_ctx, 0.f);
}

// ---------------------------------------------------------------------------
// Kernel 2: epipolar gathers + mu/var + weightNet softmax + interpolations.
// confNet logit folded in by linearity:
//   interp_emb . cnet_w = sum_n (emb[:,n] . cnet_w) * wgt[n]
// grid 16384 (s*npx), block 64.
// emb channels: sf(0..5) ce(6..69) mu(70..133) var(134..197) spa(198..199) ang(200..205)
// lane l owns ce/mu/var channel l; lanes 0..13 own the 14 extra channels.
// ---------------------------------------------------------------------------
__global__ __launch_bounds__(64) void k_epi(
    const void* __restrict__ sv, const void* __restrict__ sf, const int* __restrict__ nxy,
    const void* __restrict__ spa, const void* __restrict__ ang,
    const void* __restrict__ wnet_w, const void* __restrict__ wnet_b,
    const void* __restrict__ cnet_w,
    void* __restrict__ out)
{
    const bool F = (g_isf32 != 0);
    const int blk = blockIdx.x;
    const int b = blk >> 12, p = blk & 4095;
    const int l = threadIdx.x;

    // gather indices: n = e*3+k, dy = k-1
    int q[NSZ];
    #pragma unroll
    for (int e = 0; e < 8; ++e) {
        int nx = nxy[((b * NPX + p) * 8 + e) * 2 + 0];
        int ny = nxy[((b * NPX + p) * 8 + e) * 2 + 1];
        nx = clampi(nx, 0, 63);
        #pragma unroll
        for (int k = 0; k < 3; ++k) {
            int y = clampi(ny + k - 1, 0, 63);
            q[e * 3 + k] = y * 64 + nx;
        }
    }

    // ce channel l band
    float ceu[NSZ];
    #pragma unroll
    for (int n = 0; n < NSZ; ++n) ceu[n] = g_ce[(b * 64 + l) * NPX + q[n]];
    float mu = 0.f;
    #pragma unroll
    for (int n = 0; n < NSZ; ++n) mu += ceu[n];
    mu *= (1.f / 24.f);
    float var = 0.f;
    #pragma unroll
    for (int n = 0; n < NSZ; ++n) { float d = ceu[n] - mu; var += d * d; }
    var *= (1.f / 23.f);   // ddof=1

    const float Wce  = ldv(wnet_w, 6 + l, F);
    const float Wmu  = ldv(wnet_w, 70 + l, F);
    const float Wvar = ldv(wnet_w, 134 + l, F);
    const float Cce  = ldv(cnet_w, 6 + l, F);
    const float Cmu  = ldv(cnet_w, 70 + l, F);
    const float Cvar = ldv(cnet_w, 134 + l, F);
    const float base_w = mu * Wmu + var * Wvar;
    const float base_c = mu * Cmu + var * Cvar;
    // extra emb channel owned by lanes 0..13 (index clamped: no OOB even speculatively)
    const int   ech = (l < 6) ? l : clampi(192 + l, 198, 205);
    const float We  = (l < 14) ? ldv(wnet_w, ech, F) : 0.f;
    const float Ce  = (l < 14) ? ldv(cnet_w, ech, F) : 0.f;

    float wpart[NSZ], cpart[NSZ];
    #pragma unroll
    for (int n = 0; n < NSZ; ++n) {
        wpart[n] = ceu[n] * Wce + base_w;
        cpart[n] = ceu[n] * Cce + base_c;
    }

    if (l < 14) {
        #pragma unroll
        for (int n = 0; n < NSZ; ++n) {
            float ev;
            if (l < 6)      ev = ldv(sf, (b * 6 + l) * NPX + q[n], F);
            else if (l < 8) ev = ldv(spa, ((b * 2 + (l - 6)) * NSZ + n) * NPX + p, F);
            else            ev = ldv(ang, ((b * 6 + (l - 8)) * NSZ + n) * NPX + p, F);
            wpart[n] += ev * We;
            cpart[n] += ev * Ce;
        }
    }

    // butterfly reduce all 48 partials across the wave
    #pragma unroll
    for (int off = 32; off; off >>= 1) {
        #pragma unroll
        for (int n = 0; n < NSZ; ++n) {
            wpart[n] += __shfl_xor(wpart[n], off, 64);
            cpart[n] += __shfl_xor(cpart[n], off, 64);
        }
    }

    // softmax over nsz (weightNet)
    const float wb = ldv(wnet_b, 0, F);
    float m = wpart[0] + wb;
    #pragma unroll
    for (int n = 0; n < NSZ; ++n) { wpart[n] += wb; m = fmaxf(m, wpart[n]); }
    float ssum = 0.f;
    float wgt[NSZ];
    #pragma unroll
    for (int n = 0; n < NSZ; ++n) { wgt[n] = __expf(wpart[n] - m); ssum += wgt[n]; }
    const float inv = 1.f / ssum;
    #pragma unroll
    for (int n = 0; n < NSZ; ++n) wgt[n] *= inv;

    // confNet logit for this (source,pixel)
    float cl = 0.f;
    #pragma unroll
    for (int n = 0; n < NSZ; ++n) cl += cpart[n] * wgt[n];

    if (l == 0) {
        g_clg[b * NPX + p] = cl;
        #pragma unroll
        for (int n = 0; n < NSZ; ++n)
            stv(out, OFF3 + (b * NPX + p) * NSZ + n, wgt[n], F);   // weight [s][p][n]
    }

    // interp_ctx channel l  (layout [s*64+k][p] for the vref conv)
    float sc = 0.f;
    #pragma unroll
    for (int n = 0; n < NSZ; ++n) sc += g_ctx[(b * 64 + l) * NPX + q[n]] * wgt[n];
    g_ictx[(b * 64 + l) * NPX + p] = sc;

    // interp_view (lanes 0..2)
    if (l < 3) {
        float svv = 0.f;
        #pragma unroll
        for (int n = 0; n < NSZ; ++n) svv += ldv(sv, (b * 3 + l) * NPX + q[n], F) * wgt[n];
        g_iv[(b * NPX + p) * 3 + l] = svv;
        stv(out, OFF2 + (b * 3 + l) * NPX + p, svv, F);   // [s][c][py][px]
    }
}

// ---------------------------------------------------------------------------
// Kernel 3: confNet softmax over sources + blended image.
// grid 64 blocks x 64 threads, one thread per pixel.
// ---------------------------------------------------------------------------
__global__ __launch_bounds__(64) void k_conf(
    const void* __restrict__ cnet_b, void* __restrict__ out)
{
    const bool F = (g_isf32 != 0);
    const int p = blockIdx.x * 64 + threadIdx.x;
    const float cb = ldv(cnet_b, 0, F);

    float lg[NS];
    #pragma unroll
    for (int s = 0; s < NS; ++s) lg[s] = g_clg[s * NPX + p] + cb;
    float m = lg[0];
    #pragma unroll
    for (int s = 1; s < NS; ++s) m = fmaxf(m, lg[s]);
    float ssum = 0.f;
    float conf[NS];
    #pragma unroll
    for (int s = 0; s < NS; ++s) { conf[s] = __expf(lg[s] - m); ssum += conf[s]; }
    const float inv = 1.f / ssum;
    #pragma unroll
    for (int s = 0; s < NS; ++s) {
        conf[s] *= inv;
        stv(out, OFF4 + s * NPX + p, conf[s], F);
    }
    #pragma unroll
    for (int c = 0; c < 3; ++c) {
        float acc = 0.f;
        #pragma unroll
        for (int s = 0; s < NS; ++s)
            acc += g_iv[(s * NPX + p) * 3 + c] * conf[s];
        g_bl[c * NPX + p] = acc;
        stv(out, OFF1 + c * NPX + p, acc, F);
    }
}

// ---------------------------------------------------------------------------
// Kernel 4: psvNet — conv3x3(cat[psv_slice(3), blended(3)]) relu, mean over D
// grid 16384 (s*npx), block 64 (lane = out channel)
// ---------------------------------------------------------------------------
__global__ __launch_bounds__(64) void k_psv(
    const void* __restrict__ psvs,
    const void* __restrict__ psv_w, const void* __restrict__ psv_b)
{
    const bool F = (g_isf32 != 0);
    const int blk = blockIdx.x;
    const int s = blk >> 12, p = blk & 4095;
    const int py = p >> 6, px = p & 63;
    const int oc = threadIdx.x;

    float wreg[54];
    #pragma unroll
    for (int i = 0; i < 54; ++i) wreg[i] = ldv(psv_w, oc * 54 + i, F);  // [ic][ky][kx]
    const float bias = ldv(psv_b, oc, F);

    // blended taps (zero-padded), independent of depth
    float bconst = 0.f;
    #pragma unroll
    for (int t = 0; t < 9; ++t) {
        const int iy = py + t / 3 - 1, ix = px + t % 3 - 1;
        const bool ok = (unsigned)iy < 64u && (unsigned)ix < 64u;
        const int qq = ok ? iy * 64 + ix : 0;
        #pragma unroll
        for (int ic = 0; ic < 3; ++ic) {
            const float v = ok ? g_bl[ic * NPX + qq] : 0.f;
            bconst += v * wreg[(3 + ic) * 9 + t];
        }
    }

    float acc = 0.f;
    for (int d = 0; d < 8; ++d) {
        float a = bconst + bias;
        #pragma unroll
        for (int t = 0; t < 9; ++t) {
            const int iy = py + t / 3 - 1, ix = px + t % 3 - 1;
            if ((unsigned)iy >= 64u || (unsigned)ix >= 64u) continue;
            const int qq = iy * 64 + ix;
            #pragma unroll
            for (int ic = 0; ic < 3; ++ic)
                a += ldv(psvs, ((s * 3 + ic) * 8 + d) * NPX + qq, F) * wreg[ic * 9 + t];
        }
        acc += fmaxf(a, 0.f);
    }
    g_pf[(s * 64 + oc) * NPX + p] = acc * 0.125f;
}

// ---------------------------------------------------------------------------
// Kernel 5: vref conv3x3 over 515 channels [blended(3), ictx(256), pf(256)] -> 3
// grid 4096 (pixels), block 64
// ---------------------------------------------------------------------------
__global__ __launch_bounds__(64) void k_vref(
    const void* __restrict__ vref_w, const void* __restrict__ vref_b,
    void* __restrict__ out)
{
    const bool F = (g_isf32 != 0);
    const int p = blockIdx.x;
    const int py = p >> 6, px = p & 63;
    const int l = threadIdx.x;

    float acc[3] = {0.f, 0.f, 0.f};
    for (int ch = l; ch < 515; ch += 64) {
        #pragma unroll
        for (int t = 0; t < 9; ++t) {
            const int iy = py + t / 3 - 1, ix = px + t % 3 - 1;
            if ((unsigned)iy >= 64u || (unsigned)ix >= 64u) continue;
            const int qq = iy * 64 + ix;
            const float v = (ch < 3)   ? g_bl[ch * NPX + qq]
                          : (ch < 259) ? g_ictx[(ch - 3) * NPX + qq]
                                       : g_pf[(ch - 259) * NPX + qq];
            #pragma unroll
            for (int oc = 0; oc < 3; ++oc)
                acc[oc] += v * ldv(vref_w, (oc * 515 + ch) * 9 + t, F);
        }
    }
    #pragma unroll
    for (int off = 32; off; off >>= 1) {
        #pragma unroll
        for (int oc = 0; oc < 3; ++oc)
            acc[oc] += __shfl_xor(acc[oc], off, 64);
    }
    if (l == 0) {
        #pragma unroll
        for (int oc = 0; oc < 3; ++oc)
            stv(out, OFF0 + oc * NPX + p, acc[oc] + ldv(vref_b, oc, F), F);
    }
}

// ---------------------------------------------------------------------------
extern "C" void kernel_launch(void* const* d_in, const int* in_sizes, int n_in,
                              void* d_out, int out_size, void* d_ws, size_t ws_size,
                              hipStream_t stream)
{
    // -----------------------------------------------------------------------
    // Signature-driven input mapping: locate each tensor by its unique element
    // count (robust to scalar inputs being dropped / shifted). Falls back to
    // canonical dict positions if a size isn't found.
    // -----------------------------------------------------------------------
    auto find1 = [&](int sz, int fb) -> int {
        for (int i = 0; i < n_in; ++i) if (in_sizes[i] == sz) return i;
        return fb;
    };
    const int i_sv  = find1(49152, 0);    // source_views
    const int i_sf  = find1(98304, 1);    // source_flows
    const int i_psv = find1(393216, 2);   // psvs
    const int i_wv  = find1(147456, 3);   // warped_source_views
    const int i_nxy = find1(262144, 5);   // neighbor_xy (int32)
    const int i_spa = find1(786432, 6);   // spa_code
    const int i_ang = find1(2359296, 7);  // ang_code
    const int i_fw  = find1(10368, 9);    // flow_w
    const int i_cw  = find1(1728, 11);    // ctx_w
    const int i_pw  = find1(3456, 17);    // psv_w
    const int i_vw  = find1(13905, 19);   // vref_w
    const int i_vb  = find1(3, 20);       // vref_b
    // two 206-sized: wnet_w then cnet_w (dict order preserved)
    int i_ww = -1, i_cnw = -1;
    for (int i = 0; i < n_in; ++i)
        if (in_sizes[i] == 206) { if (i_ww < 0) i_ww = i; else { i_cnw = i; break; } }
    if (i_ww  < 0) i_ww  = 13;
    if (i_cnw < 0) i_cnw = 15;
    // three 64-sized: flow_b, ctx_b, psv_b in dict order
    int b64[3] = {10, 12, 18}; int c64 = 0;
    for (int i = 0; i < n_in && c64 < 3; ++i) if (in_sizes[i] == 64) b64[c64++] = i;
    const int i_fb = b64[0], i_cb = b64[1], i_pb = b64[2];
    // size-1 entries AFTER flow_w: wnet_b then cnet_b (band_width, if present, is before)
    int i_wb = -1, i_cnb = -1;
    for (int i = i_fw + 1; i < n_in; ++i)
        if (in_sizes[i] == 1) { if (i_wb < 0) i_wb = i; else { i_cnb = i; break; } }
    if (i_wb  < 0) i_wb  = 14;
    if (i_cnb < 0) i_cnb = 16;

    const void* sv     = d_in[i_sv];
    const void* sf     = d_in[i_sf];
    const void* psvs   = d_in[i_psv];
    const void* wv     = d_in[i_wv];
    const int*  nxy    = (const int*)d_in[i_nxy];
    const void* spa    = d_in[i_spa];
    const void* ang    = d_in[i_ang];
    const void* flow_w = d_in[i_fw];
    const void* flow_b = d_in[i_fb];
    const void* ctx_w  = d_in[i_cw];
    const void* ctx_b  = d_in[i_cb];
    const void* wnet_w = d_in[i_ww];
    const void* wnet_b = d_in[i_wb];
    const void* cnet_w = d_in[i_cnw];
    const void* cnet_b = d_in[i_cnb];
    const void* psv_w  = d_in[i_pw];
    const void* psv_b  = d_in[i_pb];
    const void* vref_w = d_in[i_vw];
    const void* vref_b = d_in[i_vb];
    (void)d_ws; (void)ws_size; (void)out_size;

    k_detect<<<1, 64, 0, stream>>>(sv);
    k_convs<<<16384, 64, 0, stream>>>(sv, sf, wv, flow_w, flow_b, ctx_w, ctx_b);
    k_epi  <<<16384, 64, 0, stream>>>(sv, sf, nxy, spa, ang, wnet_w, wnet_b, cnet_w, d_out);
    k_conf <<<64, 64, 0, stream>>>(cnet_b, d_out);
    k_psv  <<<16384, 64, 0, stream>>>(psvs, psv_w, psv_b);
    k_vref <<<4096, 64, 0, stream>>>(vref_w, vref_b, d_out);
}

// Round 6
// 417.319 us; speedup vs baseline: 2.0630x; 2.0630x over previous
//
#include <hip/hip_runtime.h>
#include <hip/hip_bf16.h>

using bf16 = __hip_bfloat16;

#define TOF(x) __bfloat162float(x)
#define TOB(x) __float2bfloat16(x)

// problem constants (fixed by harness shapes)
#define NS   4
#define NPX  4096
#define NSZ  24
#define PS   64
#define VINW 520   // 3 blended + 256 ictx + 256 pf + 5 pad

// out element offsets
#define OFF0 0        // ref_novel_view (3,4096)
#define OFF1 12288    // blended_img    (3,4096)
#define OFF2 24576    // interp_view    (4,3,4096)
#define OFF3 73728    // weight         (4,4096,24)
#define OFF4 466944   // confs          (4,4096)

// ---------------------------------------------------------------------------
// Static device-global scratch. Pixel-major (channel-last) so lane = channel
// gives coalesced access. Fully rewritten every call before any read.
// ---------------------------------------------------------------------------
__device__ float g_ce  [NS * NPX * 64];    // [s][p][ch]
__device__ float g_ctx [NS * NPX * 64];    // [s][p][ch]
__device__ float g_vin [NPX * VINW];       // [p][ch: 0-2 blended, 3-258 ictx, 259-514 pf]
__device__ float g_iv  [NS * NPX * 3];     // [s][p][c]
__device__ float g_clg [NS * NPX];         // confNet logit per (source,pixel)
__device__ float g_bl  [3 * NPX];          // blended, channel-plane (broadcast reads)
// transposed weights, f32 (lane-coalesced on the fast index)
__device__ float g_fwT [162 * 64];         // [(ic*9+t)][oc]
__device__ float g_cwT [27 * 64];          // [(ic*9+t)][oc]
__device__ float g_pwT [54 * 64];          // [(ic*9+t)][oc]
__device__ float g_vwT [3 * 9 * 515];      // [(oc*9+t)][ch]
__device__ int   g_isf32;                  // 1 = f32 inputs/outputs, 0 = bf16

__device__ __forceinline__ int clampi(int v, int lo, int hi) {
    return v < lo ? lo : (v > hi ? hi : v);
}

// dtype-dispatched load/store (F is wave-uniform)
__device__ __forceinline__ float ldv(const void* p, int i, bool f32) {
    if (f32) return ((const float*)p)[i];
    unsigned u = ((const unsigned short*)p)[i];
    return __uint_as_float(u << 16);
}
__device__ __forceinline__ void stv(void* p, int i, float v, bool f32) {
    if (f32) ((float*)p)[i] = v;
    else     ((bf16*)p)[i] = TOB(v);
}

// ---------------------------------------------------------------------------
// Kernel 0a: dtype detection (proven in round 4 — the only passing config).
// f32 data decoded as bf16 shows random-exponent garbage; bf16 data is ~N(0,1).
// ---------------------------------------------------------------------------
__global__ void k_detect(const void* sv) {
    if (threadIdx.x == 0 && blockIdx.x == 0) {
        const unsigned short* ph = (const unsigned short*)sv;
        float mh = 0.f;
        for (int i = 0; i < 512; ++i) {
            float b = __uint_as_float(((unsigned)ph[i]) << 16);
            float a = fabsf(b);
            if (!(a < 1e30f)) a = 1e30f;   // NaN/Inf counts as huge
            mh = fmaxf(mh, a);
        }
        g_isf32 = (mh > 1e6f) ? 1 : 0;
    }
}

// ---------------------------------------------------------------------------
// Kernel 0b: weight transposes into f32 caches (same work every call).
// ---------------------------------------------------------------------------
__global__ void k_prep(const void* __restrict__ fw, const void* __restrict__ cw,
                       const void* __restrict__ pw, const void* __restrict__ vw)
{
    const bool F = (g_isf32 != 0);
    const int i = blockIdx.x * 256 + threadIdx.x;
    const int stride = gridDim.x * 256;
    for (int d = i; d < 162 * 64; d += stride) g_fwT[d] = ldv(fw, (d & 63) * 162 + (d >> 6), F);
    for (int d = i; d < 27 * 64;  d += stride) g_cwT[d] = ldv(cw, (d & 63) * 27  + (d >> 6), F);
    for (int d = i; d < 54 * 64;  d += stride) g_pwT[d] = ldv(pw, (d & 63) * 54  + (d >> 6), F);
    for (int d = i; d < 13905;    d += stride) {
        int oc = d / 4635, rem = d % 4635, t = rem / 515, ch = rem % 515;
        g_vwT[d] = ldv(vw, (oc * 515 + ch) * 9 + t, F);
    }
}

// ---------------------------------------------------------------------------
// Kernel 1: ce = relu(conv3x3(cat[sf(6),sv(3),wv(9)])) ; ctx = relu(conv3x3(sv))
// grid 16384 (s*npx), block 64 (lane = out channel).
// Inputs: broadcast loads. Weights: lane-coalesced g_*wT. Stores: coalesced.
// ---------------------------------------------------------------------------
__global__ __launch_bounds__(64) void k_convs(
    const void* __restrict__ sv, const void* __restrict__ sf, const void* __restrict__ wv,
    const void* __restrict__ flow_b, const void* __restrict__ ctx_b)
{
    const bool F = (g_isf32 != 0);
    const int blk = blockIdx.x;
    const int s = blk >> 12, p = blk & 4095;
    const int py = p >> 6, px = p & 63;
    const int oc = threadIdx.x;

    float acc_ce = 0.f, acc_ctx = 0.f;
    #pragma unroll
    for (int ky = 0; ky < 3; ++ky) {
        const int iy = py + ky - 1;
        if ((unsigned)iy >= 64u) continue;
        #pragma unroll
        for (int kx = 0; kx < 3; ++kx) {
            const int ix = px + kx - 1;
            if ((unsigned)ix >= 64u) continue;
            const int q = iy * 64 + ix;
            const int t = ky * 3 + kx;
            #pragma unroll
            for (int ic = 0; ic < 6; ++ic)
                acc_ce += ldv(sf, (s * 6 + ic) * NPX + q, F) * g_fwT[(ic * 9 + t) * 64 + oc];
            #pragma unroll
            for (int ic = 0; ic < 3; ++ic) {
                const float v = ldv(sv, (s * 3 + ic) * NPX + q, F);
                acc_ce  += v * g_fwT[((6 + ic) * 9 + t) * 64 + oc];
                acc_ctx += v * g_cwT[(ic * 9 + t) * 64 + oc];
            }
            #pragma unroll
            for (int ic = 0; ic < 9; ++ic)
                acc_ce += ldv(wv, (s * 9 + ic) * NPX + q, F) * g_fwT[((9 + ic) * 9 + t) * 64 + oc];
        }
    }
    acc_ce  += ldv(flow_b, oc, F);
    acc_ctx += ldv(ctx_b, oc, F);
    g_ce [(s * NPX + p) * 64 + oc] = fmaxf(acc_ce, 0.f);
    g_ctx[(s * NPX + p) * 64 + oc] = fmaxf(acc_ctx, 0.f);
}

// ---------------------------------------------------------------------------
// Kernel 2: epipolar gathers + mu/var + weightNet softmax + interpolations.
// confNet logit folded in by linearity. grid 16384 (s*npx), block 64.
// emb channels: sf(0..5) ce(6..69) mu(70..133) var(134..197) spa(198..199) ang(200..205)
// ---------------------------------------------------------------------------
__global__ __launch_bounds__(64) void k_epi(
    const void* __restrict__ sv, const void* __restrict__ sf, const int* __restrict__ nxy,
    const void* __restrict__ spa, const void* __restrict__ ang,
    const void* __restrict__ wnet_w, const void* __restrict__ wnet_b,
    const void* __restrict__ cnet_w,
    void* __restrict__ out)
{
    const bool F = (g_isf32 != 0);
    const int blk = blockIdx.x;
    const int s = blk >> 12, p = blk & 4095;
    const int l = threadIdx.x;

    // gather indices: n = e*3+k, dy = k-1
    int q[NSZ];
    #pragma unroll
    for (int e = 0; e < 8; ++e) {
        int nx = nxy[((s * NPX + p) * 8 + e) * 2 + 0];
        int ny = nxy[((s * NPX + p) * 8 + e) * 2 + 1];
        nx = clampi(nx, 0, 63);
        #pragma unroll
        for (int k = 0; k < 3; ++k) {
            int y = clampi(ny + k - 1, 0, 63);
            q[e * 3 + k] = y * 64 + nx;
        }
    }

    // ce channel l band — coalesced lines
    float ceu[NSZ];
    #pragma unroll
    for (int n = 0; n < NSZ; ++n) ceu[n] = g_ce[(s * NPX + q[n]) * 64 + l];
    float mu = 0.f;
    #pragma unroll
    for (int n = 0; n < NSZ; ++n) mu += ceu[n];
    mu *= (1.f / 24.f);
    float var = 0.f;
    #pragma unroll
    for (int n = 0; n < NSZ; ++n) { float d = ceu[n] - mu; var += d * d; }
    var *= (1.f / 23.f);   // ddof=1

    const float Wce  = ldv(wnet_w, 6 + l, F);
    const float Wmu  = ldv(wnet_w, 70 + l, F);
    const float Wvar = ldv(wnet_w, 134 + l, F);
    const float Cce  = ldv(cnet_w, 6 + l, F);
    const float Cmu  = ldv(cnet_w, 70 + l, F);
    const float Cvar = ldv(cnet_w, 134 + l, F);
    const float base_w = mu * Wmu + var * Wvar;
    const float base_c = mu * Cmu + var * Cvar;
    const int   ech = (l < 6) ? l : clampi(192 + l, 198, 205);
    const float We  = (l < 14) ? ldv(wnet_w, ech, F) : 0.f;
    const float Ce  = (l < 14) ? ldv(cnet_w, ech, F) : 0.f;

    float wpart[NSZ], cpart[NSZ];
    #pragma unroll
    for (int n = 0; n < NSZ; ++n) {
        wpart[n] = ceu[n] * Wce + base_w;
        cpart[n] = ceu[n] * Cce + base_c;
    }

    if (l < 14) {
        #pragma unroll
        for (int n = 0; n < NSZ; ++n) {
            float ev;
            if (l < 6)      ev = ldv(sf, (s * 6 + l) * NPX + q[n], F);
            else if (l < 8) ev = ldv(spa, ((s * 2 + (l - 6)) * NSZ + n) * NPX + p, F);
            else            ev = ldv(ang, ((s * 6 + (l - 8)) * NSZ + n) * NPX + p, F);
            wpart[n] += ev * We;
            cpart[n] += ev * Ce;
        }
    }

    // butterfly reduce 48 partials across the wave
    #pragma unroll
    for (int off = 32; off; off >>= 1) {
        #pragma unroll
        for (int n = 0; n < NSZ; ++n) {
            wpart[n] += __shfl_xor(wpart[n], off, 64);
            cpart[n] += __shfl_xor(cpart[n], off, 64);
        }
    }

    // softmax over nsz (weightNet)
    const float wb = ldv(wnet_b, 0, F);
    float m = wpart[0] + wb;
    #pragma unroll
    for (int n = 0; n < NSZ; ++n) { wpart[n] += wb; m = fmaxf(m, wpart[n]); }
    float ssum = 0.f;
    #pragma unroll
    for (int n = 0; n < NSZ; ++n) { wpart[n] = __expf(wpart[n] - m); ssum += wpart[n]; }
    const float inv = 1.f / ssum;
    #pragma unroll
    for (int n = 0; n < NSZ; ++n) wpart[n] *= inv;   // wpart now = wgt

    // confNet logit
    float cl = 0.f;
    #pragma unroll
    for (int n = 0; n < NSZ; ++n) cl += cpart[n] * wpart[n];
    if (l == 0) g_clg[s * NPX + p] = cl;

    // out3: weight [s][p][n] — distributed store, lanes 0..23
    float wsel = wpart[0];
    #pragma unroll
    for (int n = 1; n < NSZ; ++n) wsel = (l == n) ? wpart[n] : wsel;
    if (l < NSZ) stv(out, OFF3 + (s * NPX + p) * NSZ + l, wsel, F);

    // interp_ctx channel l -> g_vin[p][3 + s*64 + l] (coalesced)
    float sc = 0.f;
    #pragma unroll
    for (int n = 0; n < NSZ; ++n) sc += g_ctx[(s * NPX + q[n]) * 64 + l] * wpart[n];
    g_vin[p * VINW + 3 + s * 64 + l] = sc;

    // interp_view (lanes 0..2)
    if (l < 3) {
        float svv = 0.f;
        #pragma unroll
        for (int n = 0; n < NSZ; ++n) svv += ldv(sv, (s * 3 + l) * NPX + q[n], F) * wpart[n];
        g_iv[(s * NPX + p) * 3 + l] = svv;
        stv(out, OFF2 + (s * 3 + l) * NPX + p, svv, F);
    }
}

// ---------------------------------------------------------------------------
// Kernel 3: confNet softmax over sources + blended image. 1 thread / pixel.
// ---------------------------------------------------------------------------
__global__ __launch_bounds__(64) void k_conf(
    const void* __restrict__ cnet_b, void* __restrict__ out)
{
    const bool F = (g_isf32 != 0);
    const int p = blockIdx.x * 64 + threadIdx.x;
    const float cb = ldv(cnet_b, 0, F);

    float lg[NS];
    #pragma unroll
    for (int s = 0; s < NS; ++s) lg[s] = g_clg[s * NPX + p] + cb;
    float m = lg[0];
    #pragma unroll
    for (int s = 1; s < NS; ++s) m = fmaxf(m, lg[s]);
    float ssum = 0.f;
    float conf[NS];
    #pragma unroll
    for (int s = 0; s < NS; ++s) { conf[s] = __expf(lg[s] - m); ssum += conf[s]; }
    const float inv = 1.f / ssum;
    #pragma unroll
    for (int s = 0; s < NS; ++s) {
        conf[s] *= inv;
        stv(out, OFF4 + s * NPX + p, conf[s], F);
    }
    #pragma unroll
    for (int c = 0; c < 3; ++c) {
        float acc = 0.f;
        #pragma unroll
        for (int s = 0; s < NS; ++s)
            acc += g_iv[(s * NPX + p) * 3 + c] * conf[s];
        g_bl[c * NPX + p] = acc;
        g_vin[p * VINW + c] = acc;
        stv(out, OFF1 + c * NPX + p, acc, F);
    }
}

// ---------------------------------------------------------------------------
// Kernel 4: psvNet — conv3x3(cat[psv_slice(3), blended(3)]) relu, mean over D
// grid 16384 (s*npx), block 64 (lane = oc). Weights lane-coalesced (g_pwT).
// ---------------------------------------------------------------------------
__global__ __launch_bounds__(64) void k_psv(
    const void* __restrict__ psvs, const void* __restrict__ psv_b)
{
    const bool F = (g_isf32 != 0);
    const int blk = blockIdx.x;
    const int s = blk >> 12, p = blk & 4095;
    const int py = p >> 6, px = p & 63;
    const int oc = threadIdx.x;

    float wreg[54];
    #pragma unroll
    for (int i = 0; i < 54; ++i) wreg[i] = g_pwT[i * 64 + oc];  // [ic*9+t][oc]
    const float bias = ldv(psv_b, oc, F);

    // blended taps (zero-padded), independent of depth
    float bconst = 0.f;
    #pragma unroll
    for (int t = 0; t < 9; ++t) {
        const int iy = py + t / 3 - 1, ix = px + t % 3 - 1;
        const bool ok = (unsigned)iy < 64u && (unsigned)ix < 64u;
        const int qq = ok ? iy * 64 + ix : 0;
        #pragma unroll
        for (int ic = 0; ic < 3; ++ic) {
            const float v = ok ? g_bl[ic * NPX + qq] : 0.f;
            bconst += v * wreg[(3 + ic) * 9 + t];
        }
    }

    float acc = 0.f;
    for (int d = 0; d < 8; ++d) {
        float a = bconst + bias;
        #pragma unroll
        for (int t = 0; t < 9; ++t) {
            const int iy = py + t / 3 - 1, ix = px + t % 3 - 1;
            if ((unsigned)iy >= 64u || (unsigned)ix >= 64u) continue;
            const int qq = iy * 64 + ix;
            #pragma unroll
            for (int ic = 0; ic < 3; ++ic)
                a += ldv(psvs, ((s * 3 + ic) * 8 + d) * NPX + qq, F) * wreg[ic * 9 + t];
        }
        acc += fmaxf(a, 0.f);
    }
    g_vin[p * VINW + 259 + s * 64 + oc] = acc * 0.125f;
}

// ---------------------------------------------------------------------------
// Kernel 5: vref conv3x3 over 515 channels (g_vin) -> 3. grid 4096, block 64.
// ---------------------------------------------------------------------------
__global__ __launch_bounds__(64) void k_vref(
    const void* __restrict__ vref_b, void* __restrict__ out)
{
    const bool F = (g_isf32 != 0);
    const int p = blockIdx.x;
    const int py = p >> 6, px = p & 63;
    const int l = threadIdx.x;

    float acc[3] = {0.f, 0.f, 0.f};
    #pragma unroll
    for (int k = 0; k < 9; ++k) {
        const int ch = k * 64 + l;
        if (ch >= 515) break;
        #pragma unroll
        for (int t = 0; t < 9; ++t) {
            const int iy = py + t / 3 - 1, ix = px + t % 3 - 1;
            if ((unsigned)iy >= 64u || (unsigned)ix >= 64u) continue;
            const float v = g_vin[(iy * 64 + ix) * VINW + ch];
            #pragma unroll
            for (int oc = 0; oc < 3; ++oc)
                acc[oc] += v * g_vwT[(oc * 9 + t) * 515 + ch];
        }
    }
    #pragma unroll
    for (int off = 32; off; off >>= 1) {
        #pragma unroll
        for (int oc = 0; oc < 3; ++oc)
            acc[oc] += __shfl_xor(acc[oc], off, 64);
    }
    if (l == 0) {
        #pragma unroll
        for (int oc = 0; oc < 3; ++oc)
            stv(out, OFF0 + oc * NPX + p, acc[oc] + ldv(vref_b, oc, F), F);
    }
}

// ---------------------------------------------------------------------------
extern "C" void kernel_launch(void* const* d_in, const int* in_sizes, int n_in,
                              void* d_out, int out_size, void* d_ws, size_t ws_size,
                              hipStream_t stream)
{
    // Size-based input mapping (round-4 fix: band_width may not be materialized,
    // shifting positional indices).
    auto find1 = [&](int sz, int fb) -> int {
        for (int i = 0; i < n_in; ++i) if (in_sizes[i] == sz) return i;
        return fb;
    };
    const int i_sv  = find1(49152, 0);
    const int i_sf  = find1(98304, 1);
    const int i_psv = find1(393216, 2);
    const int i_wv  = find1(147456, 3);
    const int i_nxy = find1(262144, 5);
    const int i_spa = find1(786432, 6);
    const int i_ang = find1(2359296, 7);
    const int i_fw  = find1(10368, 9);
    const int i_cw  = find1(1728, 11);
    const int i_pw  = find1(3456, 17);
    const int i_vw  = find1(13905, 19);
    const int i_vb  = find1(3, 20);
    int i_ww = -1, i_cnw = -1;
    for (int i = 0; i < n_in; ++i)
        if (in_sizes[i] == 206) { if (i_ww < 0) i_ww = i; else { i_cnw = i; break; } }
    if (i_ww  < 0) i_ww  = 13;
    if (i_cnw < 0) i_cnw = 15;
    int b64[3] = {10, 12, 18}; int c64 = 0;
    for (int i = 0; i < n_in && c64 < 3; ++i) if (in_sizes[i] == 64) b64[c64++] = i;
    const int i_fb = b64[0], i_cb = b64[1], i_pb = b64[2];
    int i_wb = -1, i_cnb = -1;
    for (int i = i_fw + 1; i < n_in; ++i)
        if (in_sizes[i] == 1) { if (i_wb < 0) i_wb = i; else { i_cnb = i; break; } }
    if (i_wb  < 0) i_wb  = 14;
    if (i_cnb < 0) i_cnb = 16;

    const void* sv     = d_in[i_sv];
    const void* sf     = d_in[i_sf];
    const void* psvs   = d_in[i_psv];
    const void* wv     = d_in[i_wv];
    const int*  nxy    = (const int*)d_in[i_nxy];
    const void* spa    = d_in[i_spa];
    const void* ang    = d_in[i_ang];
    const void* flow_w = d_in[i_fw];
    const void* flow_b = d_in[i_fb];
    const void* ctx_w  = d_in[i_cw];
    const void* ctx_b  = d_in[i_cb];
    const void* wnet_w = d_in[i_ww];
    const void* wnet_b = d_in[i_wb];
    const void* cnet_w = d_in[i_cnw];
    const void* cnet_b = d_in[i_cnb];
    const void* psv_w  = d_in[i_pw];
    const void* psv_b  = d_in[i_pb];
    const void* vref_w = d_in[i_vw];
    const void* vref_b = d_in[i_vb];
    (void)d_ws; (void)ws_size; (void)out_size;

    k_detect<<<1, 64, 0, stream>>>(sv);
    k_prep <<<64, 256, 0, stream>>>(flow_w, ctx_w, psv_w, vref_w);
    k_convs<<<16384, 64, 0, stream>>>(sv, sf, wv, flow_b, ctx_b);
    k_epi  <<<16384, 64, 0, stream>>>(sv, sf, nxy, spa, ang, wnet_w, wnet_b, cnet_w, d_out);
    k_conf <<<64, 64, 0, stream>>>(cnet_b, d_out);
    k_psv  <<<16384, 64, 0, stream>>>(psvs, psv_b);
    k_vref <<<4096, 64, 0, stream>>>(vref_b, d_out);
}

// Round 7
// 318.468 us; speedup vs baseline: 2.7033x; 1.3104x over previous
//
#include <hip/hip_runtime.h>
#include <hip/hip_bf16.h>

// Inputs/outputs are f32 (PROVEN empirically: round-5 hard-coded bf16 -> NaN;
// rounds 4/6 passed only via the runtime detector choosing the f32 path).
// Hard-coding f32 removes the per-load branch diamonds that serialized loads.

// problem constants (fixed by harness shapes)
#define NS   4
#define NPX  4096
#define NSZ  24
#define PS   64
#define VINW 520   // 3 blended + 256 ictx + 256 pf + 5 pad

// out element offsets
#define OFF0 0        // ref_novel_view (3,4096)
#define OFF1 12288    // blended_img    (3,4096)
#define OFF2 24576    // interp_view    (4,3,4096)
#define OFF3 73728    // weight         (4,4096,24)
#define OFF4 466944   // confs          (4,4096)

// ---------------------------------------------------------------------------
// Static device-global scratch. Pixel-major (channel-last) so lane = channel
// gives coalesced access. Fully rewritten every call before any read.
// ---------------------------------------------------------------------------
__device__ float g_ce  [NS * NPX * 64];    // [s][p][ch]
__device__ float g_ctx [NS * NPX * 64];    // [s][p][ch]
__device__ float g_vin [NPX * VINW];       // [p][ch: 0-2 blended, 3-258 ictx, 259-514 pf]
__device__ float g_iv  [NS * NPX * 3];     // [s][p][c]
__device__ float g_clg [NS * NPX];         // confNet logit per (source,pixel)
__device__ float g_bl  [3 * NPX];          // blended, channel-plane (broadcast reads)
// transposed weights (lane-coalesced on the fast index)
__device__ float g_fwT [162 * 64];         // [(ic*9+t)][oc]
__device__ float g_cwT [27 * 64];          // [(ic*9+t)][oc]
__device__ float g_pwT [54 * 64];          // [(ic*9+t)][oc]
__device__ float g_vwT [3 * 9 * 515];      // [(oc*9+t)][ch]

__device__ __forceinline__ int clampi(int v, int lo, int hi) {
    return v < lo ? lo : (v > hi ? hi : v);
}

// ---------------------------------------------------------------------------
// Kernel 0: weight transposes (same work every call).
// ---------------------------------------------------------------------------
__global__ void k_prep(const float* __restrict__ fw, const float* __restrict__ cw,
                       const float* __restrict__ pw, const float* __restrict__ vw)
{
    const int i = blockIdx.x * 256 + threadIdx.x;
    const int stride = gridDim.x * 256;
    for (int d = i; d < 162 * 64; d += stride) g_fwT[d] = fw[(d & 63) * 162 + (d >> 6)];
    for (int d = i; d < 27 * 64;  d += stride) g_cwT[d] = cw[(d & 63) * 27  + (d >> 6)];
    for (int d = i; d < 54 * 64;  d += stride) g_pwT[d] = pw[(d & 63) * 54  + (d >> 6)];
    for (int d = i; d < 13905;    d += stride) {
        int oc = d / 4635, rem = d % 4635, t = rem / 515, ch = rem % 515;
        g_vwT[d] = vw[(oc * 515 + ch) * 9 + t];
    }
}

// ---------------------------------------------------------------------------
// Kernel 1: ce = relu(conv3x3(cat[sf(6),sv(3),wv(9)])) ; ctx = relu(conv3x3(sv))
// grid 16384 (s*npx), block 64 (lane = out channel).
// ---------------------------------------------------------------------------
__global__ __launch_bounds__(64) void k_convs(
    const float* __restrict__ sv, const float* __restrict__ sf, const float* __restrict__ wv,
    const float* __restrict__ flow_b, const float* __restrict__ ctx_b)
{
    const int blk = blockIdx.x;
    const int s = blk >> 12, p = blk & 4095;
    const int py = p >> 6, px = p & 63;
    const int oc = threadIdx.x;

    float acc_ce = 0.f, acc_ctx = 0.f;
    #pragma unroll
    for (int ky = 0; ky < 3; ++ky) {
        const int iy = py + ky - 1;
        if ((unsigned)iy >= 64u) continue;
        #pragma unroll
        for (int kx = 0; kx < 3; ++kx) {
            const int ix = px + kx - 1;
            if ((unsigned)ix >= 64u) continue;
            const int q = iy * 64 + ix;
            const int t = ky * 3 + kx;
            #pragma unroll
            for (int ic = 0; ic < 6; ++ic)
                acc_ce += sf[(s * 6 + ic) * NPX + q] * g_fwT[(ic * 9 + t) * 64 + oc];
            #pragma unroll
            for (int ic = 0; ic < 3; ++ic) {
                const float v = sv[(s * 3 + ic) * NPX + q];
                acc_ce  += v * g_fwT[((6 + ic) * 9 + t) * 64 + oc];
                acc_ctx += v * g_cwT[(ic * 9 + t) * 64 + oc];
            }
            #pragma unroll
            for (int ic = 0; ic < 9; ++ic)
                acc_ce += wv[(s * 9 + ic) * NPX + q] * g_fwT[((9 + ic) * 9 + t) * 64 + oc];
        }
    }
    acc_ce  += flow_b[oc];
    acc_ctx += ctx_b[oc];
    g_ce [(s * NPX + p) * 64 + oc] = fmaxf(acc_ce, 0.f);
    g_ctx[(s * NPX + p) * 64 + oc] = fmaxf(acc_ctx, 0.f);
}

// ---------------------------------------------------------------------------
// Kernel 2: epipolar gathers + mu/var + weightNet softmax + interpolations.
// confNet logit folded in by linearity. grid 16384 (s*npx), block 64.
// emb channels: sf(0..5) ce(6..69) mu(70..133) var(134..197) spa(198..199) ang(200..205)
// ---------------------------------------------------------------------------
__global__ __launch_bounds__(64) void k_epi(
    const float* __restrict__ sv, const float* __restrict__ sf, const int* __restrict__ nxy,
    const float* __restrict__ spa, const float* __restrict__ ang,
    const float* __restrict__ wnet_w, const float* __restrict__ wnet_b,
    const float* __restrict__ cnet_w,
    float* __restrict__ out)
{
    const int blk = blockIdx.x;
    const int s = blk >> 12, p = blk & 4095;
    const int l = threadIdx.x;

    // gather indices: n = e*3+k, dy = k-1
    int q[NSZ];
    #pragma unroll
    for (int e = 0; e < 8; ++e) {
        int nx = nxy[((s * NPX + p) * 8 + e) * 2 + 0];
        int ny = nxy[((s * NPX + p) * 8 + e) * 2 + 1];
        nx = clampi(nx, 0, 63);
        #pragma unroll
        for (int k = 0; k < 3; ++k) {
            int y = clampi(ny + k - 1, 0, 63);
            q[e * 3 + k] = y * 64 + nx;
        }
    }

    // ce channel l band — coalesced 256B lines
    float ceu[NSZ];
    #pragma unroll
    for (int n = 0; n < NSZ; ++n) ceu[n] = g_ce[(s * NPX + q[n]) * 64 + l];
    float mu = 0.f;
    #pragma unroll
    for (int n = 0; n < NSZ; ++n) mu += ceu[n];
    mu *= (1.f / 24.f);
    float var = 0.f;
    #pragma unroll
    for (int n = 0; n < NSZ; ++n) { float d = ceu[n] - mu; var += d * d; }
    var *= (1.f / 23.f);   // ddof=1

    const float Wce  = wnet_w[6 + l];
    const float Wmu  = wnet_w[70 + l];
    const float Wvar = wnet_w[134 + l];
    const float Cce  = cnet_w[6 + l];
    const float Cmu  = cnet_w[70 + l];
    const float Cvar = cnet_w[134 + l];
    const float base_w = mu * Wmu + var * Wvar;
    const float base_c = mu * Cmu + var * Cvar;
    const int   ech = (l < 6) ? l : clampi(192 + l, 198, 205);
    const float We  = (l < 14) ? wnet_w[ech] : 0.f;
    const float Ce  = (l < 14) ? cnet_w[ech] : 0.f;

    float wpart[NSZ], cpart[NSZ];
    #pragma unroll
    for (int n = 0; n < NSZ; ++n) {
        wpart[n] = ceu[n] * Wce + base_w;
        cpart[n] = ceu[n] * Cce + base_c;
    }

    if (l < 14) {
        #pragma unroll
        for (int n = 0; n < NSZ; ++n) {
            float ev;
            if (l < 6)      ev = sf[(s * 6 + l) * NPX + q[n]];
            else if (l < 8) ev = spa[((s * 2 + (l - 6)) * NSZ + n) * NPX + p];
            else            ev = ang[((s * 6 + (l - 8)) * NSZ + n) * NPX + p];
            wpart[n] += ev * We;
            cpart[n] += ev * Ce;
        }
    }

    // butterfly reduce 48 partials across the wave
    #pragma unroll
    for (int off = 32; off; off >>= 1) {
        #pragma unroll
        for (int n = 0; n < NSZ; ++n) {
            wpart[n] += __shfl_xor(wpart[n], off, 64);
            cpart[n] += __shfl_xor(cpart[n], off, 64);
        }
    }

    // softmax over nsz (weightNet)
    const float wb = wnet_b[0];
    float m = wpart[0] + wb;
    #pragma unroll
    for (int n = 0; n < NSZ; ++n) { wpart[n] += wb; m = fmaxf(m, wpart[n]); }
    float ssum = 0.f;
    #pragma unroll
    for (int n = 0; n < NSZ; ++n) { wpart[n] = __expf(wpart[n] - m); ssum += wpart[n]; }
    const float inv = 1.f / ssum;
    #pragma unroll
    for (int n = 0; n < NSZ; ++n) wpart[n] *= inv;   // wpart now = wgt

    // confNet logit
    float cl = 0.f;
    #pragma unroll
    for (int n = 0; n < NSZ; ++n) cl += cpart[n] * wpart[n];
    if (l == 0) g_clg[s * NPX + p] = cl;

    // out3: weight [s][p][n] — distributed store, lanes 0..23
    float wsel = wpart[0];
    #pragma unroll
    for (int n = 1; n < NSZ; ++n) wsel = (l == n) ? wpart[n] : wsel;
    if (l < NSZ) out[OFF3 + (s * NPX + p) * NSZ + l] = wsel;

    // interp_ctx channel l -> g_vin[p][3 + s*64 + l] (coalesced)
    float sc = 0.f;
    #pragma unroll
    for (int n = 0; n < NSZ; ++n) sc += g_ctx[(s * NPX + q[n]) * 64 + l] * wpart[n];
    g_vin[p * VINW + 3 + s * 64 + l] = sc;

    // interp_view (lanes 0..2)
    if (l < 3) {
        float svv = 0.f;
        #pragma unroll
        for (int n = 0; n < NSZ; ++n) svv += sv[(s * 3 + l) * NPX + q[n]] * wpart[n];
        g_iv[(s * NPX + p) * 3 + l] = svv;
        out[OFF2 + (s * 3 + l) * NPX + p] = svv;
    }
}

// ---------------------------------------------------------------------------
// Kernel 3: confNet softmax over sources + blended image. 1 thread / pixel.
// ---------------------------------------------------------------------------
__global__ __launch_bounds__(64) void k_conf(
    const float* __restrict__ cnet_b, float* __restrict__ out)
{
    const int p = blockIdx.x * 64 + threadIdx.x;
    const float cb = cnet_b[0];

    float lg[NS];
    #pragma unroll
    for (int s = 0; s < NS; ++s) lg[s] = g_clg[s * NPX + p] + cb;
    float m = lg[0];
    #pragma unroll
    for (int s = 1; s < NS; ++s) m = fmaxf(m, lg[s]);
    float ssum = 0.f;
    float conf[NS];
    #pragma unroll
    for (int s = 0; s < NS; ++s) { conf[s] = __expf(lg[s] - m); ssum += conf[s]; }
    const float inv = 1.f / ssum;
    #pragma unroll
    for (int s = 0; s < NS; ++s) {
        conf[s] *= inv;
        out[OFF4 + s * NPX + p] = conf[s];
    }
    #pragma unroll
    for (int c = 0; c < 3; ++c) {
        float acc = 0.f;
        #pragma unroll
        for (int s = 0; s < NS; ++s)
            acc += g_iv[(s * NPX + p) * 3 + c] * conf[s];
        g_bl[c * NPX + p] = acc;
        g_vin[p * VINW + c] = acc;
        out[OFF1 + c * NPX + p] = acc;
    }
}

// ---------------------------------------------------------------------------
// Kernel 4: psvNet — conv3x3(cat[psv_slice(3), blended(3)]) relu, mean over D
// grid 16384 (s*npx), block 64 (lane = oc). d-loop fully unrolled so all 216
// tap loads batch into flight together.
// ---------------------------------------------------------------------------
__global__ __launch_bounds__(64) void k_psv(
    const float* __restrict__ psvs, const float* __restrict__ psv_b)
{
    const int blk = blockIdx.x;
    const int s = blk >> 12, p = blk & 4095;
    const int py = p >> 6, px = p & 63;
    const int oc = threadIdx.x;

    float wreg[54];
    #pragma unroll
    for (int i = 0; i < 54; ++i) wreg[i] = g_pwT[i * 64 + oc];  // [ic*9+t][oc]
    const float bias = psv_b[oc];

    // blended taps (zero-padded), independent of depth
    float bconst = 0.f;
    #pragma unroll
    for (int t = 0; t < 9; ++t) {
        const int iy = py + t / 3 - 1, ix = px + t % 3 - 1;
        const bool ok = (unsigned)iy < 64u && (unsigned)ix < 64u;
        const int qq = ok ? iy * 64 + ix : 0;
        #pragma unroll
        for (int ic = 0; ic < 3; ++ic) {
            const float v = ok ? g_bl[ic * NPX + qq] : 0.f;
            bconst += v * wreg[(3 + ic) * 9 + t];
        }
    }

    float acc = 0.f;
    #pragma unroll
    for (int d = 0; d < 8; ++d) {
        float a = bconst + bias;
        #pragma unroll
        for (int t = 0; t < 9; ++t) {
            const int iy = py + t / 3 - 1, ix = px + t % 3 - 1;
            if ((unsigned)iy >= 64u || (unsigned)ix >= 64u) continue;
            const int qq = iy * 64 + ix;
            #pragma unroll
            for (int ic = 0; ic < 3; ++ic)
                a += psvs[((s * 3 + ic) * 8 + d) * NPX + qq] * wreg[ic * 9 + t];
        }
        acc += fmaxf(a, 0.f);
    }
    g_vin[p * VINW + 259 + s * 64 + oc] = acc * 0.125f;
}

// ---------------------------------------------------------------------------
// Kernel 5: vref conv3x3 over 515 channels (g_vin) -> 3. grid 4096, block 64.
// ---------------------------------------------------------------------------
__global__ __launch_bounds__(64) void k_vref(
    const float* __restrict__ vref_b, float* __restrict__ out)
{
    const int p = blockIdx.x;
    const int py = p >> 6, px = p & 63;
    const int l = threadIdx.x;

    float acc[3] = {0.f, 0.f, 0.f};
    #pragma unroll
    for (int k = 0; k < 9; ++k) {
        const int ch = k * 64 + l;
        if (ch >= 515) break;
        #pragma unroll
        for (int t = 0; t < 9; ++t) {
            const int iy = py + t / 3 - 1, ix = px + t % 3 - 1;
            if ((unsigned)iy >= 64u || (unsigned)ix >= 64u) continue;
            const float v = g_vin[(iy * 64 + ix) * VINW + ch];
            #pragma unroll
            for (int oc = 0; oc < 3; ++oc)
                acc[oc] += v * g_vwT[(oc * 9 + t) * 515 + ch];
        }
    }
    #pragma unroll
    for (int off = 32; off; off >>= 1) {
        #pragma unroll
        for (int oc = 0; oc < 3; ++oc)
            acc[oc] += __shfl_xor(acc[oc], off, 64);
    }
    if (l == 0) {
        #pragma unroll
        for (int oc = 0; oc < 3; ++oc)
            out[OFF0 + oc * NPX + p] = acc[oc] + vref_b[oc];
    }
}

// ---------------------------------------------------------------------------
extern "C" void kernel_launch(void* const* d_in, const int* in_sizes, int n_in,
                              void* d_out, int out_size, void* d_ws, size_t ws_size,
                              hipStream_t stream)
{
    // Size-based input mapping (round-4 fix: band_width may not be materialized,
    // shifting positional indices).
    auto find1 = [&](int sz, int fb) -> int {
        for (int i = 0; i < n_in; ++i) if (in_sizes[i] == sz) return i;
        return fb;
    };
    const int i_sv  = find1(49152, 0);
    const int i_sf  = find1(98304, 1);
    const int i_psv = find1(393216, 2);
    const int i_wv  = find1(147456, 3);
    const int i_nxy = find1(262144, 5);
    const int i_spa = find1(786432, 6);
    const int i_ang = find1(2359296, 7);
    const int i_fw  = find1(10368, 9);
    const int i_cw  = find1(1728, 11);
    const int i_pw  = find1(3456, 17);
    const int i_vw  = find1(13905, 19);
    const int i_vb  = find1(3, 20);
    int i_ww = -1, i_cnw = -1;
    for (int i = 0; i < n_in; ++i)
        if (in_sizes[i] == 206) { if (i_ww < 0) i_ww = i; else { i_cnw = i; break; } }
    if (i_ww  < 0) i_ww  = 13;
    if (i_cnw < 0) i_cnw = 15;
    int b64[3] = {10, 12, 18}; int c64 = 0;
    for (int i = 0; i < n_in && c64 < 3; ++i) if (in_sizes[i] == 64) b64[c64++] = i;
    const int i_fb = b64[0], i_cb = b64[1], i_pb = b64[2];
    int i_wb = -1, i_cnb = -1;
    for (int i = i_fw + 1; i < n_in; ++i)
        if (in_sizes[i] == 1) { if (i_wb < 0) i_wb = i; else { i_cnb = i; break; } }
    if (i_wb  < 0) i_wb  = 14;
    if (i_cnb < 0) i_cnb = 16;

    const float* sv     = (const float*)d_in[i_sv];
    const float* sf     = (const float*)d_in[i_sf];
    const float* psvs   = (const float*)d_in[i_psv];
    const float* wv     = (const float*)d_in[i_wv];
    const int*   nxy    = (const int*)d_in[i_nxy];
    const float* spa    = (const float*)d_in[i_spa];
    const float* ang    = (const float*)d_in[i_ang];
    const float* flow_w = (const float*)d_in[i_fw];
    const float* flow_b = (const float*)d_in[i_fb];
    const float* ctx_w  = (const float*)d_in[i_cw];
    const float* ctx_b  = (const float*)d_in[i_cb];
    const float* wnet_w = (const float*)d_in[i_ww];
    const float* wnet_b = (const float*)d_in[i_wb];
    const float* cnet_w = (const float*)d_in[i_cnw];
    const float* cnet_b = (const float*)d_in[i_cnb];
    const float* psv_w  = (const float*)d_in[i_pw];
    const float* psv_b  = (const float*)d_in[i_pb];
    const float* vref_w = (const float*)d_in[i_vw];
    const float* vref_b = (const float*)d_in[i_vb];
    (void)d_ws; (void)ws_size; (void)out_size;

    float* out = (float*)d_out;

    k_prep <<<64, 256, 0, stream>>>(flow_w, ctx_w, psv_w, vref_w);
    k_convs<<<16384, 64, 0, stream>>>(sv, sf, wv, flow_b, ctx_b);
    k_epi  <<<16384, 64, 0, stream>>>(sv, sf, nxy, spa, ang, wnet_w, wnet_b, cnet_w, out);
    k_conf <<<64, 64, 0, stream>>>(cnet_b, out);
    k_psv  <<<16384, 64, 0, stream>>>(psvs, psv_b);
    k_vref <<<4096, 64, 0, stream>>>(vref_b, out);
}

// Round 8
// 250.358 us; speedup vs baseline: 3.4387x; 1.2721x over previous
//
#include <hip/hip_runtime.h>
#include <hip/hip_bf16.h>

// Inputs/outputs are f32 (proven: round-5 bf16 -> NaN; rounds 4/6 passed on f32 path).

// problem constants (fixed by harness shapes)
#define NS   4
#define NPX  4096
#define NSZ  24
#define PS   64
#define VINW 520   // 3 blended + 256 ictx + 256 pf + 5 pad
#define CW   66    // LDS row width: 64 cols + 2-col zero halo

// out element offsets
#define OFF0 0        // ref_novel_view (3,4096)
#define OFF1 12288    // blended_img    (3,4096)
#define OFF2 24576    // interp_view    (4,3,4096)
#define OFF3 73728    // weight         (4,4096,24)
#define OFF4 466944   // confs          (4,4096)

// ---------------------------------------------------------------------------
// Static device-global scratch. Pixel-major (channel-last) so lane = channel
// gives coalesced access. Fully rewritten every call before any read.
// ---------------------------------------------------------------------------
__device__ float g_ce  [NS * NPX * 64];    // [s][p][ch]
__device__ float g_ctx [NS * NPX * 64];    // [s][p][ch]
__device__ float g_vin [NPX * VINW];       // [p][ch: 0-2 blended, 3-258 ictx, 259-514 pf]
__device__ float g_iv  [NS * NPX * 3];     // [s][p][c]
__device__ float g_clg [NS * NPX];         // confNet logit per (source,pixel)
__device__ float g_bl  [3 * NPX];          // blended, channel-plane
// transposed weights (lane-coalesced on the fast index)
__device__ float g_fwT [162 * 64];         // [(ic*9+t)][oc]
__device__ float g_cwT [27 * 64];          // [(ic*9+t)][oc]
__device__ float g_pwT [54 * 64];          // [(ic*9+t)][oc]
__device__ float g_vwT [3 * 9 * 515];      // [(oc*9+t)][ch]

__device__ __forceinline__ int clampi(int v, int lo, int hi) {
    return v < lo ? lo : (v > hi ? hi : v);
}

// ---------------------------------------------------------------------------
// Kernel 0: weight transposes (same work every call).
// ---------------------------------------------------------------------------
__global__ void k_prep(const float* __restrict__ fw, const float* __restrict__ cw,
                       const float* __restrict__ pw, const float* __restrict__ vw)
{
    const int i = blockIdx.x * 256 + threadIdx.x;
    const int stride = gridDim.x * 256;
    for (int d = i; d < 162 * 64; d += stride) g_fwT[d] = fw[(d & 63) * 162 + (d >> 6)];
    for (int d = i; d < 27 * 64;  d += stride) g_cwT[d] = cw[(d & 63) * 27  + (d >> 6)];
    for (int d = i; d < 54 * 64;  d += stride) g_pwT[d] = pw[(d & 63) * 54  + (d >> 6)];
    for (int d = i; d < 13905;    d += stride) {
        int oc = d / 4635, rem = d % 4635, t = rem / 515, ch = rem % 515;
        g_vwT[d] = vw[(oc * 515 + ch) * 9 + t];
    }
}

// ---------------------------------------------------------------------------
// Kernel 1: flowRefNet + ctxNet convs, ROW-TILED.
// block = (s, py): 256 threads = 4 waves; wave w -> px in [16w,16w+16), lane = oc.
// Stage 18 input planes x 3 rows into LDS (coalesced, zero halo), then
// broadcast ds_reads with a rolling 3-column window.
// plane order: 0..5 sf, 6..8 sv, 9..17 wv (matches flow_w ic order).
// ---------------------------------------------------------------------------
__global__ __launch_bounds__(256) void k_convs(
    const float* __restrict__ sv, const float* __restrict__ sf, const float* __restrict__ wv,
    const float* __restrict__ flow_b, const float* __restrict__ ctx_b)
{
    __shared__ float lds[18 * 3 * CW];
    const int s  = blockIdx.x >> 6, py = blockIdx.x & 63;
    const int tid = threadIdx.x;

    for (int i = tid; i < 18 * 3 * CW; i += 256) lds[i] = 0.f;
    __syncthreads();
    for (int i = tid; i < 18 * 3 * 64; i += 256) {
        const int col = i & 63;
        const int r   = (i >> 6) % 3;
        const int pl  = i / 192;
        const int iy  = py + r - 1;
        if ((unsigned)iy < 64u) {
            const float* src = (pl < 6) ? (sf + (s * 6 + pl) * NPX)
                             : (pl < 9) ? (sv + (s * 3 + (pl - 6)) * NPX)
                                        : (wv + (s * 9 + (pl - 9)) * NPX);
            lds[(pl * 3 + r) * CW + col + 1] = src[iy * 64 + col];
        }
    }
    __syncthreads();

    const int oc  = tid & 63;
    const int px0 = (tid >> 6) * 16;

    float acc_ce[16], acc_ctx[16];
    const float fb = flow_b[oc], cb = ctx_b[oc];
    #pragma unroll
    for (int j = 0; j < 16; ++j) { acc_ce[j] = fb; acc_ctx[j] = cb; }

    for (int pl = 0; pl < 18; ++pl) {
        float w[9];
        #pragma unroll
        for (int t = 0; t < 9; ++t) w[t] = g_fwT[(pl * 9 + t) * 64 + oc];
        float wc[9];
        const bool has_ctx = (pl >= 6 && pl < 9);
        if (has_ctx) {
            #pragma unroll
            for (int t = 0; t < 9; ++t) wc[t] = g_cwT[((pl - 6) * 9 + t) * 64 + oc];
        }
        float c0[3], c1[3], c2[3];
        #pragma unroll
        for (int r = 0; r < 3; ++r) {
            c0[r] = lds[(pl * 3 + r) * CW + px0];       // actual col px0-1
            c1[r] = lds[(pl * 3 + r) * CW + px0 + 1];   // actual col px0
        }
        #pragma unroll
        for (int j = 0; j < 16; ++j) {
            #pragma unroll
            for (int r = 0; r < 3; ++r)
                c2[r] = lds[(pl * 3 + r) * CW + px0 + j + 2];  // actual col px0+j+1
            float a = 0.f;
            #pragma unroll
            for (int r = 0; r < 3; ++r)
                a += c0[r] * w[r * 3 + 0] + c1[r] * w[r * 3 + 1] + c2[r] * w[r * 3 + 2];
            acc_ce[j] += a;
            if (has_ctx) {
                float b2 = 0.f;
                #pragma unroll
                for (int r = 0; r < 3; ++r)
                    b2 += c0[r] * wc[r * 3 + 0] + c1[r] * wc[r * 3 + 1] + c2[r] * wc[r * 3 + 2];
                acc_ctx[j] += b2;
            }
            #pragma unroll
            for (int r = 0; r < 3; ++r) { c0[r] = c1[r]; c1[r] = c2[r]; }
        }
    }
    #pragma unroll
    for (int j = 0; j < 16; ++j) {
        const int p = py * 64 + px0 + j;
        g_ce [(s * NPX + p) * 64 + oc] = fmaxf(acc_ce[j], 0.f);
        g_ctx[(s * NPX + p) * 64 + oc] = fmaxf(acc_ctx[j], 0.f);
    }
}

// ---------------------------------------------------------------------------
// Kernel 2: epipolar gathers + mu/var + weightNet softmax + interpolations.
// confNet logit folded in by linearity. grid 16384 (s*npx), block 64.
// emb channels: sf(0..5) ce(6..69) mu(70..133) var(134..197) spa(198..199) ang(200..205)
// ---------------------------------------------------------------------------
__global__ __launch_bounds__(64) void k_epi(
    const float* __restrict__ sv, const float* __restrict__ sf, const int* __restrict__ nxy,
    const float* __restrict__ spa, const float* __restrict__ ang,
    const float* __restrict__ wnet_w, const float* __restrict__ wnet_b,
    const float* __restrict__ cnet_w,
    float* __restrict__ out)
{
    const int blk = blockIdx.x;
    const int s = blk >> 12, p = blk & 4095;
    const int l = threadIdx.x;

    int q[NSZ];
    #pragma unroll
    for (int e = 0; e < 8; ++e) {
        int nx = nxy[((s * NPX + p) * 8 + e) * 2 + 0];
        int ny = nxy[((s * NPX + p) * 8 + e) * 2 + 1];
        nx = clampi(nx, 0, 63);
        #pragma unroll
        for (int k = 0; k < 3; ++k) {
            int y = clampi(ny + k - 1, 0, 63);
            q[e * 3 + k] = y * 64 + nx;
        }
    }

    float ceu[NSZ];
    #pragma unroll
    for (int n = 0; n < NSZ; ++n) ceu[n] = g_ce[(s * NPX + q[n]) * 64 + l];
    float mu = 0.f;
    #pragma unroll
    for (int n = 0; n < NSZ; ++n) mu += ceu[n];
    mu *= (1.f / 24.f);
    float var = 0.f;
    #pragma unroll
    for (int n = 0; n < NSZ; ++n) { float d = ceu[n] - mu; var += d * d; }
    var *= (1.f / 23.f);   // ddof=1

    const float Wce  = wnet_w[6 + l];
    const float Wmu  = wnet_w[70 + l];
    const float Wvar = wnet_w[134 + l];
    const float Cce  = cnet_w[6 + l];
    const float Cmu  = cnet_w[70 + l];
    const float Cvar = cnet_w[134 + l];
    const float base_w = mu * Wmu + var * Wvar;
    const float base_c = mu * Cmu + var * Cvar;
    const int   ech = (l < 6) ? l : clampi(192 + l, 198, 205);
    const float We  = (l < 14) ? wnet_w[ech] : 0.f;
    const float Ce  = (l < 14) ? cnet_w[ech] : 0.f;

    float wpart[NSZ], cpart[NSZ];
    #pragma unroll
    for (int n = 0; n < NSZ; ++n) {
        wpart[n] = ceu[n] * Wce + base_w;
        cpart[n] = ceu[n] * Cce + base_c;
    }

    if (l < 14) {
        #pragma unroll
        for (int n = 0; n < NSZ; ++n) {
            float ev;
            if (l < 6)      ev = sf[(s * 6 + l) * NPX + q[n]];
            else if (l < 8) ev = spa[((s * 2 + (l - 6)) * NSZ + n) * NPX + p];
            else            ev = ang[((s * 6 + (l - 8)) * NSZ + n) * NPX + p];
            wpart[n] += ev * We;
            cpart[n] += ev * Ce;
        }
    }

    #pragma unroll
    for (int off = 32; off; off >>= 1) {
        #pragma unroll
        for (int n = 0; n < NSZ; ++n) {
            wpart[n] += __shfl_xor(wpart[n], off, 64);
            cpart[n] += __shfl_xor(cpart[n], off, 64);
        }
    }

    const float wb = wnet_b[0];
    float m = wpart[0] + wb;
    #pragma unroll
    for (int n = 0; n < NSZ; ++n) { wpart[n] += wb; m = fmaxf(m, wpart[n]); }
    float ssum = 0.f;
    #pragma unroll
    for (int n = 0; n < NSZ; ++n) { wpart[n] = __expf(wpart[n] - m); ssum += wpart[n]; }
    const float inv = 1.f / ssum;
    #pragma unroll
    for (int n = 0; n < NSZ; ++n) wpart[n] *= inv;   // wpart now = wgt

    float cl = 0.f;
    #pragma unroll
    for (int n = 0; n < NSZ; ++n) cl += cpart[n] * wpart[n];
    if (l == 0) g_clg[s * NPX + p] = cl;

    float wsel = wpart[0];
    #pragma unroll
    for (int n = 1; n < NSZ; ++n) wsel = (l == n) ? wpart[n] : wsel;
    if (l < NSZ) out[OFF3 + (s * NPX + p) * NSZ + l] = wsel;

    float sc = 0.f;
    #pragma unroll
    for (int n = 0; n < NSZ; ++n) sc += g_ctx[(s * NPX + q[n]) * 64 + l] * wpart[n];
    g_vin[p * VINW + 3 + s * 64 + l] = sc;

    if (l < 3) {
        float svv = 0.f;
        #pragma unroll
        for (int n = 0; n < NSZ; ++n) svv += sv[(s * 3 + l) * NPX + q[n]] * wpart[n];
        g_iv[(s * NPX + p) * 3 + l] = svv;
        out[OFF2 + (s * 3 + l) * NPX + p] = svv;
    }
}

// ---------------------------------------------------------------------------
// Kernel 3: confNet softmax over sources + blended image. 1 thread / pixel.
// ---------------------------------------------------------------------------
__global__ __launch_bounds__(64) void k_conf(
    const float* __restrict__ cnet_b, float* __restrict__ out)
{
    const int p = blockIdx.x * 64 + threadIdx.x;
    const float cb = cnet_b[0];

    float lg[NS];
    #pragma unroll
    for (int s = 0; s < NS; ++s) lg[s] = g_clg[s * NPX + p] + cb;
    float m = lg[0];
    #pragma unroll
    for (int s = 1; s < NS; ++s) m = fmaxf(m, lg[s]);
    float ssum = 0.f;
    float conf[NS];
    #pragma unroll
    for (int s = 0; s < NS; ++s) { conf[s] = __expf(lg[s] - m); ssum += conf[s]; }
    const float inv = 1.f / ssum;
    #pragma unroll
    for (int s = 0; s < NS; ++s) {
        conf[s] *= inv;
        out[OFF4 + s * NPX + p] = conf[s];
    }
    #pragma unroll
    for (int c = 0; c < 3; ++c) {
        float acc = 0.f;
        #pragma unroll
        for (int s = 0; s < NS; ++s)
            acc += g_iv[(s * NPX + p) * 3 + c] * conf[s];
        g_bl[c * NPX + p] = acc;
        g_vin[p * VINW + c] = acc;
        out[OFF1 + c * NPX + p] = acc;
    }
}

// ---------------------------------------------------------------------------
// Kernel 4: psvNet, ROW-TILED. block = (s, py): 256 threads = 4 waves,
// wave -> 16 px, lane = oc. Planes 0..23 = psv (ic*8+d), 24..26 = blended ic.
// ---------------------------------------------------------------------------
__global__ __launch_bounds__(256) void k_psv(
    const float* __restrict__ psvs, const float* __restrict__ psv_b)
{
    __shared__ float lds[27 * 3 * CW];
    const int s  = blockIdx.x >> 6, py = blockIdx.x & 63;
    const int tid = threadIdx.x;

    for (int i = tid; i < 27 * 3 * CW; i += 256) lds[i] = 0.f;
    __syncthreads();
    for (int i = tid; i < 27 * 3 * 64; i += 256) {
        const int col = i & 63;
        const int r   = (i >> 6) % 3;
        const int pl  = i / 192;
        const int iy  = py + r - 1;
        if ((unsigned)iy < 64u) {
            const float* src = (pl < 24) ? (psvs + (s * 24 + pl) * NPX)  // pl = ic*8+d
                                         : (g_bl + (pl - 24) * NPX);
            lds[(pl * 3 + r) * CW + col + 1] = src[iy * 64 + col];
        }
    }
    __syncthreads();

    const int oc  = tid & 63;
    const int px0 = (tid >> 6) * 16;
    const float bias = psv_b[oc];

    // hoisted psv weights: wp[ic][t]
    float wp[3][9];
    #pragma unroll
    for (int ic = 0; ic < 3; ++ic)
        #pragma unroll
        for (int t = 0; t < 9; ++t) wp[ic][t] = g_pwT[(ic * 9 + t) * 64 + oc];

    // blended pre-pass -> bconst[16] (includes bias)
    float bconst[16];
    #pragma unroll
    for (int j = 0; j < 16; ++j) bconst[j] = bias;
    for (int ic = 0; ic < 3; ++ic) {
        float w[9];
        #pragma unroll
        for (int t = 0; t < 9; ++t) w[t] = g_pwT[((3 + ic) * 9 + t) * 64 + oc];
        const int pl = 24 + ic;
        float c0[3], c1[3], c2[3];
        #pragma unroll
        for (int r = 0; r < 3; ++r) {
            c0[r] = lds[(pl * 3 + r) * CW + px0];
            c1[r] = lds[(pl * 3 + r) * CW + px0 + 1];
        }
        #pragma unroll
        for (int j = 0; j < 16; ++j) {
            #pragma unroll
            for (int r = 0; r < 3; ++r)
                c2[r] = lds[(pl * 3 + r) * CW + px0 + j + 2];
            float a = 0.f;
            #pragma unroll
            for (int r = 0; r < 3; ++r)
                a += c0[r] * w[r * 3 + 0] + c1[r] * w[r * 3 + 1] + c2[r] * w[r * 3 + 2];
            bconst[j] += a;
            #pragma unroll
            for (int r = 0; r < 3; ++r) { c0[r] = c1[r]; c1[r] = c2[r]; }
        }
    }

    float acc[16];
    #pragma unroll
    for (int j = 0; j < 16; ++j) acc[j] = 0.f;

    for (int d = 0; d < 8; ++d) {
        float a[16];
        #pragma unroll
        for (int j = 0; j < 16; ++j) a[j] = bconst[j];
        #pragma unroll
        for (int ic = 0; ic < 3; ++ic) {
            const int pl = ic * 8 + d;
            float c0[3], c1[3], c2[3];
            #pragma unroll
            for (int r = 0; r < 3; ++r) {
                c0[r] = lds[(pl * 3 + r) * CW + px0];
                c1[r] = lds[(pl * 3 + r) * CW + px0 + 1];
            }
            #pragma unroll
            for (int j = 0; j < 16; ++j) {
                #pragma unroll
                for (int r = 0; r < 3; ++r)
                    c2[r] = lds[(pl * 3 + r) * CW + px0 + j + 2];
                float t2 = 0.f;
                #pragma unroll
                for (int r = 0; r < 3; ++r)
                    t2 += c0[r] * wp[ic][r * 3 + 0] + c1[r] * wp[ic][r * 3 + 1] + c2[r] * wp[ic][r * 3 + 2];
                a[j] += t2;
                #pragma unroll
                for (int r = 0; r < 3; ++r) { c0[r] = c1[r]; c1[r] = c2[r]; }
            }
        }
        #pragma unroll
        for (int j = 0; j < 16; ++j) acc[j] += fmaxf(a[j], 0.f);
    }
    #pragma unroll
    for (int j = 0; j < 16; ++j)
        g_vin[(py * 64 + px0 + j) * VINW + 259 + s * 64 + oc] = acc[j] * 0.125f;
}

// ---------------------------------------------------------------------------
// Kernel 5: vref conv3x3 over 515 channels (g_vin) -> 3. grid 4096, block 64.
// ---------------------------------------------------------------------------
__global__ __launch_bounds__(64) void k_vref(
    const float* __restrict__ vref_b, float* __restrict__ out)
{
    const int p = blockIdx.x;
    const int py = p >> 6, px = p & 63;
    const int l = threadIdx.x;

    float acc[3] = {0.f, 0.f, 0.f};
    #pragma unroll
    for (int k = 0; k < 9; ++k) {
        const int ch = k * 64 + l;
        if (ch >= 515) break;
        #pragma unroll
        for (int t = 0; t < 9; ++t) {
            const int iy = py + t / 3 - 1, ix = px + t % 3 - 1;
            if ((unsigned)iy >= 64u || (unsigned)ix >= 64u) continue;
            const float v = g_vin[(iy * 64 + ix) * VINW + ch];
            #pragma unroll
            for (int oc = 0; oc < 3; ++oc)
                acc[oc] += v * g_vwT[(oc * 9 + t) * 515 + ch];
        }
    }
    #pragma unroll
    for (int off = 32; off; off >>= 1) {
        #pragma unroll
        for (int oc = 0; oc < 3; ++oc)
            acc[oc] += __shfl_xor(acc[oc], off, 64);
    }
    if (l == 0) {
        #pragma unroll
        for (int oc = 0; oc < 3; ++oc)
            out[OFF0 + oc * NPX + p] = acc[oc] + vref_b[oc];
    }
}

// ---------------------------------------------------------------------------
extern "C" void kernel_launch(void* const* d_in, const int* in_sizes, int n_in,
                              void* d_out, int out_size, void* d_ws, size_t ws_size,
                              hipStream_t stream)
{
    auto find1 = [&](int sz, int fb) -> int {
        for (int i = 0; i < n_in; ++i) if (in_sizes[i] == sz) return i;
        return fb;
    };
    const int i_sv  = find1(49152, 0);
    const int i_sf  = find1(98304, 1);
    const int i_psv = find1(393216, 2);
    const int i_wv  = find1(147456, 3);
    const int i_nxy = find1(262144, 5);
    const int i_spa = find1(786432, 6);
    const int i_ang = find1(2359296, 7);
    const int i_fw  = find1(10368, 9);
    const int i_cw  = find1(1728, 11);
    const int i_pw  = find1(3456, 17);
    const int i_vw  = find1(13905, 19);
    const int i_vb  = find1(3, 20);
    int i_ww = -1, i_cnw = -1;
    for (int i = 0; i < n_in; ++i)
        if (in_sizes[i] == 206) { if (i_ww < 0) i_ww = i; else { i_cnw = i; break; } }
    if (i_ww  < 0) i_ww  = 13;
    if (i_cnw < 0) i_cnw = 15;
    int b64[3] = {10, 12, 18}; int c64 = 0;
    for (int i = 0; i < n_in && c64 < 3; ++i) if (in_sizes[i] == 64) b64[c64++] = i;
    const int i_fb = b64[0], i_cb = b64[1], i_pb = b64[2];
    int i_wb = -1, i_cnb = -1;
    for (int i = i_fw + 1; i < n_in; ++i)
        if (in_sizes[i] == 1) { if (i_wb < 0) i_wb = i; else { i_cnb = i; break; } }
    if (i_wb  < 0) i_wb  = 14;
    if (i_cnb < 0) i_cnb = 16;

    const float* sv     = (const float*)d_in[i_sv];
    const float* sf     = (const float*)d_in[i_sf];
    const float* psvs   = (const float*)d_in[i_psv];
    const float* wv     = (const float*)d_in[i_wv];
    const int*   nxy    = (const int*)d_in[i_nxy];
    const float* spa    = (const float*)d_in[i_spa];
    const float* ang    = (const float*)d_in[i_ang];
    const float* flow_w = (const float*)d_in[i_fw];
    const float* flow_b = (const float*)d_in[i_fb];
    const float* ctx_w  = (const float*)d_in[i_cw];
    const float* ctx_b  = (const float*)d_in[i_cb];
    const float* wnet_w = (const float*)d_in[i_ww];
    const float* wnet_b = (const float*)d_in[i_wb];
    const float* cnet_w = (const float*)d_in[i_cnw];
    const float* cnet_b = (const float*)d_in[i_cnb];
    const float* psv_w  = (const float*)d_in[i_pw];
    const float* psv_b  = (const float*)d_in[i_pb];
    const float* vref_w = (const float*)d_in[i_vw];
    const float* vref_b = (const float*)d_in[i_vb];
    (void)d_ws; (void)ws_size; (void)out_size;

    float* out = (float*)d_out;

    k_prep <<<64, 256, 0, stream>>>(flow_w, ctx_w, psv_w, vref_w);
    k_convs<<<256, 256, 0, stream>>>(sv, sf, wv, flow_b, ctx_b);
    k_epi  <<<16384, 64, 0, stream>>>(sv, sf, nxy, spa, ang, wnet_w, wnet_b, cnet_w, out);
    k_conf <<<64, 64, 0, stream>>>(cnet_b, out);
    k_psv  <<<256, 256, 0, stream>>>(psvs, psv_b);
    k_vref <<<4096, 64, 0, stream>>>(vref_b, out);
}

// Round 9
// 237.070 us; speedup vs baseline: 3.6315x; 1.0561x over previous
//
#include <hip/hip_runtime.h>
#include <hip/hip_bf16.h>

// Inputs/outputs are f32 (proven: round-5 bf16 -> NaN; rounds 4/6 passed on f32 path).

// problem constants (fixed by harness shapes)
#define NS   4
#define NPX  4096
#define NSZ  24
#define PS   64
#define VINW 520   // 3 blended + 256 ictx + 256 pf + 5 pad
#define CW   66    // LDS row width: 64 cols + 2-col zero halo

// out element offsets
#define OFF0 0        // ref_novel_view (3,4096)
#define OFF1 12288    // blended_img    (3,4096)
#define OFF2 24576    // interp_view    (4,3,4096)
#define OFF3 73728    // weight         (4,4096,24)
#define OFF4 466944   // confs          (4,4096)

// ---------------------------------------------------------------------------
// Static device-global scratch. Pixel-major so lane = channel is coalesced.
// g_cc packs ce (lo bf16) + ctx (hi bf16) per channel: the k_epi gather working
// set drops 32 MB -> 4 MB (~ one XCD L2) and gather lines halve.
// ---------------------------------------------------------------------------
__device__ unsigned       g_cc  [NS * NPX * 64];   // [s][p][ch]: lo=ce, hi=ctx (bf16)
__device__ unsigned short g_vin [NPX * VINW];      // bf16 [p][ch: 0-2 bl, 3-258 ictx, 259-514 pf]
__device__ float g_iv  [NS * NPX * 3];    // [s][p][c]
__device__ float g_clg [NS * NPX];        // confNet logit per (source,pixel)
__device__ float g_bl  [3 * NPX];         // blended, channel-plane (f32)
// transposed weights (lane-coalesced on the fast index)
__device__ float g_fwT [162 * 64];        // [(ic*9+t)][oc]
__device__ float g_cwT [27 * 64];         // [(ic*9+t)][oc]
__device__ float g_pwT [54 * 64];         // [(ic*9+t)][oc]
__device__ float g_vwT [3 * 9 * 515];     // [(oc*9+t)][ch]

__device__ __forceinline__ int clampi(int v, int lo, int hi) {
    return v < lo ? lo : (v > hi ? hi : v);
}
__device__ __forceinline__ unsigned bf16_bits(float f) {   // RNE f32->bf16 bits
    unsigned u = __float_as_uint(f);
    return (u + 0x7fffu + ((u >> 16) & 1u)) >> 16;
}
__device__ __forceinline__ float bf16_lo(unsigned v) { return __uint_as_float(v << 16); }
__device__ __forceinline__ float bf16_hi(unsigned v) { return __uint_as_float(v & 0xffff0000u); }
__device__ __forceinline__ float ldbf(const unsigned short* p, int i) {
    return __uint_as_float(((unsigned)p[i]) << 16);
}

// ---------------------------------------------------------------------------
// Kernel 0: weight transposes (same work every call).
// ---------------------------------------------------------------------------
__global__ void k_prep(const float* __restrict__ fw, const float* __restrict__ cw,
                       const float* __restrict__ pw, const float* __restrict__ vw)
{
    const int i = blockIdx.x * 256 + threadIdx.x;
    const int stride = gridDim.x * 256;
    for (int d = i; d < 162 * 64; d += stride) g_fwT[d] = fw[(d & 63) * 162 + (d >> 6)];
    for (int d = i; d < 27 * 64;  d += stride) g_cwT[d] = cw[(d & 63) * 27  + (d >> 6)];
    for (int d = i; d < 54 * 64;  d += stride) g_pwT[d] = pw[(d & 63) * 54  + (d >> 6)];
    for (int d = i; d < 13905;    d += stride) {
        int oc = d / 4635, rem = d % 4635, t = rem / 515, ch = rem % 515;
        g_vwT[d] = vw[(oc * 515 + ch) * 9 + t];
    }
}

// ---------------------------------------------------------------------------
// Kernel 1: flowRefNet + ctxNet convs, ROW-TILED.
// block = (s, py): 256 threads = 4 waves; wave w -> px in [16w,16w+16), lane = oc.
// ---------------------------------------------------------------------------
__global__ __launch_bounds__(256) void k_convs(
    const float* __restrict__ sv, const float* __restrict__ sf, const float* __restrict__ wv,
    const float* __restrict__ flow_b, const float* __restrict__ ctx_b)
{
    __shared__ float lds[18 * 3 * CW];
    const int s  = blockIdx.x >> 6, py = blockIdx.x & 63;
    const int tid = threadIdx.x;

    for (int i = tid; i < 18 * 3 * CW; i += 256) lds[i] = 0.f;
    __syncthreads();
    for (int i = tid; i < 18 * 3 * 64; i += 256) {
        const int col = i & 63;
        const int r   = (i >> 6) % 3;
        const int pl  = i / 192;
        const int iy  = py + r - 1;
        if ((unsigned)iy < 64u) {
            const float* src = (pl < 6) ? (sf + (s * 6 + pl) * NPX)
                             : (pl < 9) ? (sv + (s * 3 + (pl - 6)) * NPX)
                                        : (wv + (s * 9 + (pl - 9)) * NPX);
            lds[(pl * 3 + r) * CW + col + 1] = src[iy * 64 + col];
        }
    }
    __syncthreads();

    const int oc  = tid & 63;
    const int px0 = (tid >> 6) * 16;

    float acc_ce[16], acc_ctx[16];
    const float fb = flow_b[oc], cb = ctx_b[oc];
    #pragma unroll
    for (int j = 0; j < 16; ++j) { acc_ce[j] = fb; acc_ctx[j] = cb; }

    for (int pl = 0; pl < 18; ++pl) {
        float w[9];
        #pragma unroll
        for (int t = 0; t < 9; ++t) w[t] = g_fwT[(pl * 9 + t) * 64 + oc];
        float wc[9];
        const bool has_ctx = (pl >= 6 && pl < 9);
        if (has_ctx) {
            #pragma unroll
            for (int t = 0; t < 9; ++t) wc[t] = g_cwT[((pl - 6) * 9 + t) * 64 + oc];
        }
        float c0[3], c1[3], c2[3];
        #pragma unroll
        for (int r = 0; r < 3; ++r) {
            c0[r] = lds[(pl * 3 + r) * CW + px0];
            c1[r] = lds[(pl * 3 + r) * CW + px0 + 1];
        }
        #pragma unroll
        for (int j = 0; j < 16; ++j) {
            #pragma unroll
            for (int r = 0; r < 3; ++r)
                c2[r] = lds[(pl * 3 + r) * CW + px0 + j + 2];
            float a = 0.f;
            #pragma unroll
            for (int r = 0; r < 3; ++r)
                a += c0[r] * w[r * 3 + 0] + c1[r] * w[r * 3 + 1] + c2[r] * w[r * 3 + 2];
            acc_ce[j] += a;
            if (has_ctx) {
                float b2 = 0.f;
                #pragma unroll
                for (int r = 0; r < 3; ++r)
                    b2 += c0[r] * wc[r * 3 + 0] + c1[r] * wc[r * 3 + 1] + c2[r] * wc[r * 3 + 2];
                acc_ctx[j] += b2;
            }
            #pragma unroll
            for (int r = 0; r < 3; ++r) { c0[r] = c1[r]; c1[r] = c2[r]; }
        }
    }
    #pragma unroll
    for (int j = 0; j < 16; ++j) {
        const int p = py * 64 + px0 + j;
        g_cc[(s * NPX + p) * 64 + oc] =
            bf16_bits(fmaxf(acc_ce[j], 0.f)) | (bf16_bits(fmaxf(acc_ctx[j], 0.f)) << 16);
    }
}

// ---------------------------------------------------------------------------
// Kernel 2: epipolar gathers + mu/var + weightNet softmax + interpolations.
// One dword gather per band element gives both ce (lo) and ctx (hi).
// Butterfly reduces only wpart (24); confNet logit reduced as one scalar after.
// ---------------------------------------------------------------------------
__global__ __launch_bounds__(64) void k_epi(
    const float* __restrict__ sv, const float* __restrict__ sf, const int* __restrict__ nxy,
    const float* __restrict__ spa, const float* __restrict__ ang,
    const float* __restrict__ wnet_w, const float* __restrict__ wnet_b,
    const float* __restrict__ cnet_w,
    float* __restrict__ out)
{
    const int blk = blockIdx.x;
    const int s = blk >> 12, p = blk & 4095;
    const int l = threadIdx.x;

    int q[NSZ];
    #pragma unroll
    for (int e = 0; e < 8; ++e) {
        int nx = nxy[((s * NPX + p) * 8 + e) * 2 + 0];
        int ny = nxy[((s * NPX + p) * 8 + e) * 2 + 1];
        nx = clampi(nx, 0, 63);
        #pragma unroll
        for (int k = 0; k < 3; ++k) {
            int y = clampi(ny + k - 1, 0, 63);
            q[e * 3 + k] = y * 64 + nx;
        }
    }

    const unsigned* ccp = g_cc + (size_t)s * NPX * 64;
    unsigned cc[NSZ];
    #pragma unroll
    for (int n = 0; n < NSZ; ++n) cc[n] = ccp[q[n] * 64 + l];

    float mu = 0.f;
    #pragma unroll
    for (int n = 0; n < NSZ; ++n) mu += bf16_lo(cc[n]);
    mu *= (1.f / 24.f);

    const float Wce  = wnet_w[6 + l];
    const float Cce  = cnet_w[6 + l];
    float var = 0.f;
    float wpart[NSZ], cpart[NSZ];
    #pragma unroll
    for (int n = 0; n < NSZ; ++n) {
        const float ce = bf16_lo(cc[n]);
        const float d = ce - mu;
        var += d * d;
        wpart[n] = ce * Wce;
        cpart[n] = ce * Cce;
    }
    var *= (1.f / 23.f);   // ddof=1

    const float base_w = mu * wnet_w[70 + l] + var * wnet_w[134 + l];
    const float base_c = mu * cnet_w[70 + l] + var * cnet_w[134 + l];
    const int   ech = (l < 6) ? l : clampi(192 + l, 198, 205);
    const float We  = (l < 14) ? wnet_w[ech] : 0.f;
    const float Ce  = (l < 14) ? cnet_w[ech] : 0.f;

    if (l < 14) {
        #pragma unroll
        for (int n = 0; n < NSZ; ++n) {
            float ev;
            if (l < 6)      ev = sf[(s * 6 + l) * NPX + q[n]];
            else if (l < 8) ev = spa[((s * 2 + (l - 6)) * NSZ + n) * NPX + p];
            else            ev = ang[((s * 6 + (l - 8)) * NSZ + n) * NPX + p];
            wpart[n] += ev * We + base_w;
            cpart[n] += ev * Ce + base_c;
        }
    } else {
        #pragma unroll
        for (int n = 0; n < NSZ; ++n) { wpart[n] += base_w; cpart[n] += base_c; }
    }

    // butterfly reduce the 24 weight-logits only
    #pragma unroll
    for (int off = 32; off; off >>= 1) {
        #pragma unroll
        for (int n = 0; n < NSZ; ++n)
            wpart[n] += __shfl_xor(wpart[n], off, 64);
    }

    // softmax over nsz (weightNet)
    const float wb = wnet_b[0];
    float m = wpart[0] + wb;
    #pragma unroll
    for (int n = 0; n < NSZ; ++n) { wpart[n] += wb; m = fmaxf(m, wpart[n]); }
    float ssum = 0.f;
    #pragma unroll
    for (int n = 0; n < NSZ; ++n) { wpart[n] = __expf(wpart[n] - m); ssum += wpart[n]; }
    const float inv = 1.f / ssum;
    #pragma unroll
    for (int n = 0; n < NSZ; ++n) wpart[n] *= inv;   // wpart now = wgt (all lanes)

    // confNet logit: per-lane channel contribution, single scalar butterfly
    float cl = 0.f;
    #pragma unroll
    for (int n = 0; n < NSZ; ++n) cl += cpart[n] * wpart[n];
    #pragma unroll
    for (int off = 32; off; off >>= 1) cl += __shfl_xor(cl, off, 64);
    if (l == 0) g_clg[s * NPX + p] = cl;

    // out3: weight [s][p][n] — distributed store, lanes 0..23
    float wsel = wpart[0];
    #pragma unroll
    for (int n = 1; n < NSZ; ++n) wsel = (l == n) ? wpart[n] : wsel;
    if (l < NSZ) out[OFF3 + (s * NPX + p) * NSZ + l] = wsel;

    // interp_ctx channel l (ctx = hi half of the same gathered dwords)
    float sc = 0.f;
    #pragma unroll
    for (int n = 0; n < NSZ; ++n) sc += bf16_hi(cc[n]) * wpart[n];
    g_vin[p * VINW + 3 + s * 64 + l] = (unsigned short)bf16_bits(sc);

    // interp_view (lanes 0..2)
    if (l < 3) {
        float svv = 0.f;
        #pragma unroll
        for (int n = 0; n < NSZ; ++n) svv += sv[(s * 3 + l) * NPX + q[n]] * wpart[n];
        g_iv[(s * NPX + p) * 3 + l] = svv;
        out[OFF2 + (s * 3 + l) * NPX + p] = svv;
    }
}

// ---------------------------------------------------------------------------
// Kernel 3: confNet softmax over sources + blended image. 1 thread / pixel.
// ---------------------------------------------------------------------------
__global__ __launch_bounds__(64) void k_conf(
    const float* __restrict__ cnet_b, float* __restrict__ out)
{
    const int p = blockIdx.x * 64 + threadIdx.x;
    const float cb = cnet_b[0];

    float lg[NS];
    #pragma unroll
    for (int s = 0; s < NS; ++s) lg[s] = g_clg[s * NPX + p] + cb;
    float m = lg[0];
    #pragma unroll
    for (int s = 1; s < NS; ++s) m = fmaxf(m, lg[s]);
    float ssum = 0.f;
    float conf[NS];
    #pragma unroll
    for (int s = 0; s < NS; ++s) { conf[s] = __expf(lg[s] - m); ssum += conf[s]; }
    const float inv = 1.f / ssum;
    #pragma unroll
    for (int s = 0; s < NS; ++s) {
        conf[s] *= inv;
        out[OFF4 + s * NPX + p] = conf[s];
    }
    #pragma unroll
    for (int c = 0; c < 3; ++c) {
        float acc = 0.f;
        #pragma unroll
        for (int s = 0; s < NS; ++s)
            acc += g_iv[(s * NPX + p) * 3 + c] * conf[s];
        g_bl[c * NPX + p] = acc;
        g_vin[p * VINW + c] = (unsigned short)bf16_bits(acc);
        out[OFF1 + c * NPX + p] = acc;
    }
}

// ---------------------------------------------------------------------------
// Kernel 4: psvNet, ROW-TILED. block = (s, py): 256 threads = 4 waves,
// wave -> 16 px, lane = oc. Planes 0..23 = psv (ic*8+d), 24..26 = blended ic.
// ---------------------------------------------------------------------------
__global__ __launch_bounds__(256) void k_psv(
    const float* __restrict__ psvs, const float* __restrict__ psv_b)
{
    __shared__ float lds[27 * 3 * CW];
    const int s  = blockIdx.x >> 6, py = blockIdx.x & 63;
    const int tid = threadIdx.x;

    for (int i = tid; i < 27 * 3 * CW; i += 256) lds[i] = 0.f;
    __syncthreads();
    for (int i = tid; i < 27 * 3 * 64; i += 256) {
        const int col = i & 63;
        const int r   = (i >> 6) % 3;
        const int pl  = i / 192;
        const int iy  = py + r - 1;
        if ((unsigned)iy < 64u) {
            const float* src = (pl < 24) ? (psvs + (s * 24 + pl) * NPX)
                                         : (g_bl + (pl - 24) * NPX);
            lds[(pl * 3 + r) * CW + col + 1] = src[iy * 64 + col];
        }
    }
    __syncthreads();

    const int oc  = tid & 63;
    const int px0 = (tid >> 6) * 16;
    const float bias = psv_b[oc];

    float wp[3][9];
    #pragma unroll
    for (int ic = 0; ic < 3; ++ic)
        #pragma unroll
        for (int t = 0; t < 9; ++t) wp[ic][t] = g_pwT[(ic * 9 + t) * 64 + oc];

    float bconst[16];
    #pragma unroll
    for (int j = 0; j < 16; ++j) bconst[j] = bias;
    for (int ic = 0; ic < 3; ++ic) {
        float w[9];
        #pragma unroll
        for (int t = 0; t < 9; ++t) w[t] = g_pwT[((3 + ic) * 9 + t) * 64 + oc];
        const int pl = 24 + ic;
        float c0[3], c1[3], c2[3];
        #pragma unroll
        for (int r = 0; r < 3; ++r) {
            c0[r] = lds[(pl * 3 + r) * CW + px0];
            c1[r] = lds[(pl * 3 + r) * CW + px0 + 1];
        }
        #pragma unroll
        for (int j = 0; j < 16; ++j) {
            #pragma unroll
            for (int r = 0; r < 3; ++r)
                c2[r] = lds[(pl * 3 + r) * CW + px0 + j + 2];
            float a = 0.f;
            #pragma unroll
            for (int r = 0; r < 3; ++r)
                a += c0[r] * w[r * 3 + 0] + c1[r] * w[r * 3 + 1] + c2[r] * w[r * 3 + 2];
            bconst[j] += a;
            #pragma unroll
            for (int r = 0; r < 3; ++r) { c0[r] = c1[r]; c1[r] = c2[r]; }
        }
    }

    float acc[16];
    #pragma unroll
    for (int j = 0; j < 16; ++j) acc[j] = 0.f;

    for (int d = 0; d < 8; ++d) {
        float a[16];
        #pragma unroll
        for (int j = 0; j < 16; ++j) a[j] = bconst[j];
        #pragma unroll
        for (int ic = 0; ic < 3; ++ic) {
            const int pl = ic * 8 + d;
            float c0[3], c1[3], c2[3];
            #pragma unroll
            for (int r = 0; r < 3; ++r) {
                c0[r] = lds[(pl * 3 + r) * CW + px0];
                c1[r] = lds[(pl * 3 + r) * CW + px0 + 1];
            }
            #pragma unroll
            for (int j = 0; j < 16; ++j) {
                #pragma unroll
                for (int r = 0; r < 3; ++r)
                    c2[r] = lds[(pl * 3 + r) * CW + px0 + j + 2];
                float t2 = 0.f;
                #pragma unroll
                for (int r = 0; r < 3; ++r)
                    t2 += c0[r] * wp[ic][r * 3 + 0] + c1[r] * wp[ic][r * 3 + 1] + c2[r] * wp[ic][r * 3 + 2];
                a[j] += t2;
                #pragma unroll
                for (int r = 0; r < 3; ++r) { c0[r] = c1[r]; c1[r] = c2[r]; }
            }
        }
        #pragma unroll
        for (int j = 0; j < 16; ++j) acc[j] += fmaxf(a[j], 0.f);
    }
    #pragma unroll
    for (int j = 0; j < 16; ++j)
        g_vin[(py * 64 + px0 + j) * VINW + 259 + s * 64 + oc] =
            (unsigned short)bf16_bits(acc[j] * 0.125f);
}

// ---------------------------------------------------------------------------
// Kernel 5: vref conv3x3 over 515 channels (g_vin, bf16) -> 3. grid 4096, block 64.
// ---------------------------------------------------------------------------
__global__ __launch_bounds__(64) void k_vref(
    const float* __restrict__ vref_b, float* __restrict__ out)
{
    const int p = blockIdx.x;
    const int py = p >> 6, px = p & 63;
    const int l = threadIdx.x;

    float acc[3] = {0.f, 0.f, 0.f};
    #pragma unroll
    for (int k = 0; k < 9; ++k) {
        const int ch = k * 64 + l;
        if (ch >= 515) break;
        #pragma unroll
        for (int t = 0; t < 9; ++t) {
            const int iy = py + t / 3 - 1, ix = px + t % 3 - 1;
            if ((unsigned)iy >= 64u || (unsigned)ix >= 64u) continue;
            const float v = ldbf(g_vin, (iy * 64 + ix) * VINW + ch);
            #pragma unroll
            for (int oc = 0; oc < 3; ++oc)
                acc[oc] += v * g_vwT[(oc * 9 + t) * 515 + ch];
        }
    }
    #pragma unroll
    for (int off = 32; off; off >>= 1) {
        #pragma unroll
        for (int oc = 0; oc < 3; ++oc)
            acc[oc] += __shfl_xor(acc[oc], off, 64);
    }
    if (l == 0) {
        #pragma unroll
        for (int oc = 0; oc < 3; ++oc)
            out[OFF0 + oc * NPX + p] = acc[oc] + vref_b[oc];
    }
}

// ---------------------------------------------------------------------------
extern "C" void kernel_launch(void* const* d_in, const int* in_sizes, int n_in,
                              void* d_out, int out_size, void* d_ws, size_t ws_size,
                              hipStream_t stream)
{
    auto find1 = [&](int sz, int fb) -> int {
        for (int i = 0; i < n_in; ++i) if (in_sizes[i] == sz) return i;
        return fb;
    };
    const int i_sv  = find1(49152, 0);
    const int i_sf  = find1(98304, 1);
    const int i_psv = find1(393216, 2);
    const int i_wv  = find1(147456, 3);
    const int i_nxy = find1(262144, 5);
    const int i_spa = find1(786432, 6);
    const int i_ang = find1(2359296, 7);
    const int i_fw  = find1(10368, 9);
    const int i_cw  = find1(1728, 11);
    const int i_pw  = find1(3456, 17);
    const int i_vw  = find1(13905, 19);
    const int i_vb  = find1(3, 20);
    int i_ww = -1, i_cnw = -1;
    for (int i = 0; i < n_in; ++i)
        if (in_sizes[i] == 206) { if (i_ww < 0) i_ww = i; else { i_cnw = i; break; } }
    if (i_ww  < 0) i_ww  = 13;
    if (i_cnw < 0) i_cnw = 15;
    int b64[3] = {10, 12, 18}; int c64 = 0;
    for (int i = 0; i < n_in && c64 < 3; ++i) if (in_sizes[i] == 64) b64[c64++] = i;
    const int i_fb = b64[0], i_cb = b64[1], i_pb = b64[2];
    int i_wb = -1, i_cnb = -1;
    for (int i = i_fw + 1; i < n_in; ++i)
        if (in_sizes[i] == 1) { if (i_wb < 0) i_wb = i; else { i_cnb = i; break; } }
    if (i_wb  < 0) i_wb  = 14;
    if (i_cnb < 0) i_cnb = 16;

    const float* sv     = (const float*)d_in[i_sv];
    const float* sf     = (const float*)d_in[i_sf];
    const float* psvs   = (const float*)d_in[i_psv];
    const float* wv     = (const float*)d_in[i_wv];
    const int*   nxy    = (const int*)d_in[i_nxy];
    const float* spa    = (const float*)d_in[i_spa];
    const float* ang    = (const float*)d_in[i_ang];
    const float* flow_w = (const float*)d_in[i_fw];
    const float* flow_b = (const float*)d_in[i_fb];
    const float* ctx_w  = (const float*)d_in[i_cw];
    const float* ctx_b  = (const float*)d_in[i_cb];
    const float* wnet_w = (const float*)d_in[i_ww];
    const float* wnet_b = (const float*)d_in[i_wb];
    const float* cnet_w = (const float*)d_in[i_cnw];
    const float* cnet_b = (const float*)d_in[i_cnb];
    const float* psv_w  = (const float*)d_in[i_pw];
    const float* psv_b  = (const float*)d_in[i_pb];
    const float* vref_w = (const float*)d_in[i_vw];
    const float* vref_b = (const float*)d_in[i_vb];
    (void)d_ws; (void)ws_size; (void)out_size;

    float* out = (float*)d_out;

    k_prep <<<64, 256, 0, stream>>>(flow_w, ctx_w, psv_w, vref_w);
    k_convs<<<256, 256, 0, stream>>>(sv, sf, wv, flow_b, ctx_b);
    k_epi  <<<16384, 64, 0, stream>>>(sv, sf, nxy, spa, ang, wnet_w, wnet_b, cnet_w, out);
    k_conf <<<64, 64, 0, stream>>>(cnet_b, out);
    k_psv  <<<256, 256, 0, stream>>>(psvs, psv_b);
    k_vref <<<4096, 64, 0, stream>>>(vref_b, out);
}